// Round 1
// baseline (1283.680 us; speedup 1.0000x reference)
//
#include <hip/hip_runtime.h>
#include <hip/hip_bf16.h>
#include <stdint.h>

using bf16_t = __bf16;
using bf16x8 = __attribute__((ext_vector_type(8))) __bf16;
using bf16x4 = __attribute__((ext_vector_type(4))) __bf16;
using f32x4  = __attribute__((ext_vector_type(4))) float;

#define D_MODEL 3072
#define N_HEADS 24
#define HEAD_DIM 128
#define Q_PROJ 1536
#define KV_PROJ 2048
#define ROPE_DIM 64
#define S_LEN 2048
#define NTOK 4096            // B*S
#define KVDN 2112            // KV_PROJ + ROPE_DIM
#define KVUN 4608            // D_MODEL + N_HEADS*ROPE_DIM

// ---- async global->LDS (16B per lane, wave-uniform LDS base) ----
__device__ __forceinline__ void async_ld16(const void* g, void* l) {
    __builtin_amdgcn_global_load_lds(
        (__attribute__((address_space(1))) uint32_t*)(uintptr_t)g,
        (__attribute__((address_space(3))) uint32_t*)(uint32_t)(uintptr_t)l,
        16, 0, 0);
}

// =====================  RMSNorm (fp32 in -> bf16 out)  =====================
__global__ __launch_bounds__(256) void rmsnorm_kernel(
    const float* __restrict__ x, const float* __restrict__ sc, bf16_t* __restrict__ xn)
{
    const int tok = blockIdx.x;
    const int t = threadIdx.x;
    const float4* xr = (const float4*)(x + (size_t)tok * D_MODEL);
    float4 a = xr[t], b = xr[t + 256], c = xr[t + 512];
    float ss = a.x*a.x + a.y*a.y + a.z*a.z + a.w*a.w
             + b.x*b.x + b.y*b.y + b.z*b.z + b.w*b.w
             + c.x*c.x + c.y*c.y + c.z*c.z + c.w*c.w;
    #pragma unroll
    for (int off = 32; off >= 1; off >>= 1) ss += __shfl_xor(ss, off);
    __shared__ float red[4];
    if ((t & 63) == 0) red[t >> 6] = ss;
    __syncthreads();
    const float inv = rsqrtf((red[0] + red[1] + red[2] + red[3]) * (1.0f / D_MODEL) + 1e-6f);
    const float4* sr = (const float4*)sc;
    float4 s0 = sr[t], s1 = sr[t + 256], s2 = sr[t + 512];
    bf16x4* xo = (bf16x4*)(xn + (size_t)tok * D_MODEL);
    bf16x4 o;
    o[0]=(bf16_t)(a.x*s0.x*inv); o[1]=(bf16_t)(a.y*s0.y*inv); o[2]=(bf16_t)(a.z*s0.z*inv); o[3]=(bf16_t)(a.w*s0.w*inv);
    xo[t] = o;
    o[0]=(bf16_t)(b.x*s1.x*inv); o[1]=(bf16_t)(b.y*s1.y*inv); o[2]=(bf16_t)(b.z*s1.z*inv); o[3]=(bf16_t)(b.w*s1.w*inv);
    xo[t + 256] = o;
    o[0]=(bf16_t)(c.x*s2.x*inv); o[1]=(bf16_t)(c.y*s2.y*inv); o[2]=(bf16_t)(c.z*s2.z*inv); o[3]=(bf16_t)(c.w*s2.w*inv);
    xo[t + 512] = o;
}

// ============  weight transpose fp32 (K x N) -> bf16 B^T (N x K)  ============
__global__ void transpose_conv(const float* __restrict__ in, bf16_t* __restrict__ out, int K, int N)
{
    __shared__ float tile[32][33];
    const int n0 = blockIdx.x * 32, k0 = blockIdx.y * 32;
    const int tx = threadIdx.x, ty = threadIdx.y;
    #pragma unroll
    for (int i = 0; i < 32; i += 8)
        tile[ty + i][tx] = in[(size_t)(k0 + ty + i) * N + n0 + tx];
    __syncthreads();
    #pragma unroll
    for (int i = 0; i < 32; i += 8)
        out[(size_t)(n0 + ty + i) * K + k0 + tx] = (bf16_t)tile[tx][ty + i];
}

// ==================  plain fp32 -> bf16 conversion (w_o)  ==================
__global__ void conv_bf16(const float* __restrict__ in, bf16_t* __restrict__ out, int n4)
{
    const int stride = gridDim.x * 256;
    for (int i = blockIdx.x * 256 + threadIdx.x; i < n4; i += stride) {
        float4 v = ((const float4*)in)[i];
        bf16x4 o;
        o[0] = (bf16_t)v.x; o[1] = (bf16_t)v.y; o[2] = (bf16_t)v.z; o[3] = (bf16_t)v.w;
        ((bf16x4*)out)[i] = o;
    }
}

// =====  GEMM: C[m,n] = sum_k A[m,k]*B[n,k];  A M x K bf16, B N x K bf16  =====
// m97 structure: 128x128 tile, BK=32, 4 waves (each 64x64), global_load_lds w16.
__global__ __launch_bounds__(256) void gemm_bt(
    const bf16_t* __restrict__ A, const bf16_t* __restrict__ B,
    float* __restrict__ Cf, int ldcf,
    bf16_t* __restrict__ Cb, int ldcb, int nbmax,
    int M, int N, int K)
{
    __shared__ bf16_t As[128 * 32];
    __shared__ bf16_t Bs[128 * 32];
    const int t = threadIdx.x;
    const int wave = t >> 6, lane = t & 63;
    const int m0 = blockIdx.y * 128, n0 = blockIdx.x * 128;
    const int wm = (wave >> 1) * 64, wn = (wave & 1) * 64;
    const int lrow = lane >> 2;
    const int lcol = (lane & 3) * 8;
    const int c0 = wave, c1 = wave + 4;

    const int ar0 = m0 + c0 * 16 + lrow;
    const int ar1 = m0 + c1 * 16 + lrow;
    int br0 = n0 + c0 * 16 + lrow; if (br0 > N - 1) br0 = N - 1;
    int br1 = n0 + c1 * 16 + lrow; if (br1 > N - 1) br1 = N - 1;
    const bf16_t* ap0 = A + (size_t)ar0 * K + lcol;
    const bf16_t* ap1 = A + (size_t)ar1 * K + lcol;
    const bf16_t* bp0 = B + (size_t)br0 * K + lcol;
    const bf16_t* bp1 = B + (size_t)br1 * K + lcol;
    bf16_t* lA0 = As + c0 * 512;
    bf16_t* lA1 = As + c1 * 512;
    bf16_t* lB0 = Bs + c0 * 512;
    bf16_t* lB1 = Bs + c1 * 512;

    f32x4 zero = {0.f, 0.f, 0.f, 0.f};
    f32x4 acc[4][4];
    #pragma unroll
    for (int i = 0; i < 4; ++i)
        #pragma unroll
        for (int j = 0; j < 4; ++j) acc[i][j] = zero;

    const int fr = lane & 15;
    const int fk = (lane >> 4) * 8;

    for (int k0 = 0; k0 < K; k0 += 32) {
        async_ld16(ap0 + k0, lA0);
        async_ld16(ap1 + k0, lA1);
        async_ld16(bp0 + k0, lB0);
        async_ld16(bp1 + k0, lB1);
        __syncthreads();                    // drains vmcnt, staging visible
        bf16x8 af[4], bfv[4];
        #pragma unroll
        for (int i = 0; i < 4; ++i) af[i] = *(const bf16x8*)(As + (wm + i * 16 + fr) * 32 + fk);
        #pragma unroll
        for (int j = 0; j < 4; ++j) bfv[j] = *(const bf16x8*)(Bs + (wn + j * 16 + fr) * 32 + fk);
        #pragma unroll
        for (int i = 0; i < 4; ++i)
            #pragma unroll
            for (int j = 0; j < 4; ++j)
                acc[i][j] = __builtin_amdgcn_mfma_f32_16x16x32_bf16(af[i], bfv[j], acc[i][j], 0, 0, 0);
        __syncthreads();                    // reads done before next stage
    }

    const int colb = n0 + wn + fr;
    const int rowb = m0 + wm + (lane >> 4) * 4;
    #pragma unroll
    for (int i = 0; i < 4; ++i) {
        #pragma unroll
        for (int j = 0; j < 4; ++j) {
            const int col = colb + j * 16;
            #pragma unroll
            for (int r = 0; r < 4; ++r) {
                const int row = rowb + i * 16 + r;
                const float v = acc[i][j][r];
                if (Cf && col < N)     Cf[(size_t)row * ldcf + col] = v;
                if (Cb && col < nbmax) Cb[(size_t)row * ldcb + col] = (bf16_t)v;
            }
        }
    }
}

// =========================  RoPE tables (fp32)  =========================
__global__ void rope_tab(float* __restrict__ ctab, float* __restrict__ stab)
{
    const int idx = blockIdx.x * 256 + threadIdx.x;
    if (idx >= S_LEN * 32) return;
    const int s = idx >> 5, i = idx & 31;
    const float freq = powf(10000.0f, -(float)(2 * i) * (1.0f / 128.0f));
    const float ang = (float)s * freq;
    ctab[idx] = cosf(ang);
    stab[idx] = sinf(ang);
}

// =================  RoPE on Q (in-place, dims 64..127/head)  =================
__global__ void rope_q_kernel(bf16_t* __restrict__ q, const float* __restrict__ ctab,
                              const float* __restrict__ stab)
{
    const int idx = blockIdx.x * 256 + threadIdx.x;
    if (idx >= NTOK * N_HEADS * 32) return;
    const int i = idx & 31;
    const int rest = idx >> 5;
    const int h = rest % N_HEADS;
    const int tok = rest / N_HEADS;
    const int s = tok & (S_LEN - 1);
    bf16_t* p = q + (size_t)tok * D_MODEL + h * HEAD_DIM + 64;
    const float a = (float)p[i], b = (float)p[i + 32];
    const float c = ctab[s * 32 + i], sn = stab[s * 32 + i];
    p[i]      = (bf16_t)(a * c - b * sn);
    p[i + 32] = (bf16_t)(b * c + a * sn);
}

// ==========  RoPE on shared K-rope (reads kv_down fp32 output)  ==========
__global__ void rope_k_kernel(const float* __restrict__ kvd, bf16_t* __restrict__ kr,
                              const float* __restrict__ ctab, const float* __restrict__ stab)
{
    const int idx = blockIdx.x * 256 + threadIdx.x;
    if (idx >= NTOK * 32) return;
    const int i = idx & 31;
    const int tok = idx >> 5;
    const int s = tok & (S_LEN - 1);
    const float* p = kvd + (size_t)tok * KVDN + KV_PROJ;
    const float a = p[i], b = p[i + 32];
    const float c = ctab[s * 32 + i], sn = stab[s * 32 + i];
    kr[(size_t)tok * 64 + i]      = (bf16_t)(a * c - b * sn);
    kr[(size_t)tok * 64 + i + 32] = (bf16_t)(b * c + a * sn);
}

// ======  V transpose: VT[bh][d][s] = kv_up[b, s, h*192 + 64 + d]  ======
__global__ void vt_asm(const bf16_t* __restrict__ kvup, bf16_t* __restrict__ vt)
{
    __shared__ bf16_t tile[32][33];
    const int s0 = blockIdx.x * 32, d0 = blockIdx.y * 32, bh = blockIdx.z;
    const int b = bh / N_HEADS, h = bh % N_HEADS;
    const int tx = threadIdx.x, ty = threadIdx.y;
    #pragma unroll
    for (int i = 0; i < 32; i += 8)
        tile[ty + i][tx] = kvup[(size_t)(b * S_LEN + s0 + ty + i) * KVUN + h * 192 + 64 + d0 + tx];
    __syncthreads();
    #pragma unroll
    for (int i = 0; i < 32; i += 8)
        vt[((size_t)bh * HEAD_DIM + d0 + ty + i) * S_LEN + s0 + tx] = tile[tx][ty + i];
}

// =====================  causal flash attention  =====================
// Q: (NTOK, 3072) roped; KVUP: (NTOK,4608) [K-norope at h*192+0..63];
// KR: (NTOK,64); VT: (48,128,2048); AO: (NTOK,3072) = attn_out (b,s,h,d)
__global__ __launch_bounds__(256) void attn_fwd(
    const bf16_t* __restrict__ Q, const bf16_t* __restrict__ KVUP,
    const bf16_t* __restrict__ KR, const bf16_t* __restrict__ VT,
    bf16_t* __restrict__ AO)
{
    __shared__ bf16_t Plds[4 * 16 * 64];
    const int bh = blockIdx.y;
    const int b = bh / N_HEADS, h = bh % N_HEADS;
    const int qt = blockIdx.x;
    const int wave = threadIdx.x >> 6, lane = threadIdx.x & 63;
    const int fr = lane & 15, fg = lane >> 4;
    const int qbase = qt * 64 + wave * 16;

    const bf16_t* qrow = Q + (size_t)(b * S_LEN + qbase + fr) * D_MODEL + h * HEAD_DIM;
    bf16x8 qf[4];
    #pragma unroll
    for (int kc = 0; kc < 4; ++kc) qf[kc] = *(const bf16x8*)(qrow + kc * 32 + fg * 8);

    f32x4 zero = {0.f, 0.f, 0.f, 0.f};
    f32x4 oacc[8];
    #pragma unroll
    for (int nf = 0; nf < 8; ++nf) oacc[nf] = zero;
    float m_i[4], l_i[4];
    #pragma unroll
    for (int r = 0; r < 4; ++r) { m_i[r] = -1e30f; l_i[r] = 0.f; }

    const bf16_t* Kb  = KVUP + (size_t)b * S_LEN * KVUN + (size_t)h * 192;
    const bf16_t* KRb = KR + (size_t)b * S_LEN * 64;
    const bf16_t* Vb  = VT + (size_t)bh * HEAD_DIM * S_LEN;
    bf16_t* P = Plds + wave * (16 * 64);
    const float isc = 0.08838834764831843f;   // 1/sqrt(128)
    const int kvend = qbase + 16;

    for (int kvb = 0; kvb < kvend; kvb += 64) {
        f32x4 sacc[4];
        #pragma unroll
        for (int jn = 0; jn < 4; ++jn) sacc[jn] = zero;
        #pragma unroll
        for (int jn = 0; jn < 4; ++jn) {
            const int kvr = kvb + jn * 16 + fr;
            const bf16_t* krow = Kb + (size_t)kvr * KVUN;
            const bf16_t* krr  = KRb + (size_t)kvr * 64;
            bf16x8 k0 = *(const bf16x8*)(krow + fg * 8);
            bf16x8 k1 = *(const bf16x8*)(krow + 32 + fg * 8);
            bf16x8 k2 = *(const bf16x8*)(krr + fg * 8);
            bf16x8 k3 = *(const bf16x8*)(krr + 32 + fg * 8);
            sacc[jn] = __builtin_amdgcn_mfma_f32_16x16x32_bf16(qf[0], k0, sacc[jn], 0, 0, 0);
            sacc[jn] = __builtin_amdgcn_mfma_f32_16x16x32_bf16(qf[1], k1, sacc[jn], 0, 0, 0);
            sacc[jn] = __builtin_amdgcn_mfma_f32_16x16x32_bf16(qf[2], k2, sacc[jn], 0, 0, 0);
            sacc[jn] = __builtin_amdgcn_mfma_f32_16x16x32_bf16(qf[3], k3, sacc[jn], 0, 0, 0);
        }
        // scale + causal mask + row max
        float mrow[4];
        #pragma unroll
        for (int r = 0; r < 4; ++r) {
            const int row = qbase + fg * 4 + r;
            float mx = -1e30f;
            #pragma unroll
            for (int jn = 0; jn < 4; ++jn) {
                float v = sacc[jn][r] * isc;
                if (kvb + jn * 16 + fr > row) v = -1e30f;
                sacc[jn][r] = v;
                mx = fmaxf(mx, v);
            }
            mrow[r] = mx;
        }
        #pragma unroll
        for (int off = 1; off < 16; off <<= 1)
            #pragma unroll
            for (int r = 0; r < 4; ++r)
                mrow[r] = fmaxf(mrow[r], __shfl_xor(mrow[r], off));
        float scf[4], lsum[4];
        #pragma unroll
        for (int r = 0; r < 4; ++r) {
            const float mn = fmaxf(m_i[r], mrow[r]);
            scf[r] = __expf(m_i[r] - mn);
            m_i[r] = mn;
        }
        #pragma unroll
        for (int r = 0; r < 4; ++r) {
            float s = 0.f;
            #pragma unroll
            for (int jn = 0; jn < 4; ++jn) {
                const float p = __expf(sacc[jn][r] - m_i[r]);
                sacc[jn][r] = p;
                s += p;
            }
            lsum[r] = s;
        }
        #pragma unroll
        for (int off = 1; off < 16; off <<= 1)
            #pragma unroll
            for (int r = 0; r < 4; ++r)
                lsum[r] += __shfl_xor(lsum[r], off);
        #pragma unroll
        for (int r = 0; r < 4; ++r) l_i[r] = l_i[r] * scf[r] + lsum[r];
        #pragma unroll
        for (int nf = 0; nf < 8; ++nf)
            #pragma unroll
            for (int r = 0; r < 4; ++r)
                oacc[nf][r] *= scf[r];
        // P (D-layout) -> LDS -> A-layout fragments
        #pragma unroll
        for (int jn = 0; jn < 4; ++jn)
            #pragma unroll
            for (int r = 0; r < 4; ++r)
                P[(fg * 4 + r) * 64 + jn * 16 + fr] = (bf16_t)sacc[jn][r];
        asm volatile("s_waitcnt lgkmcnt(0)" ::: "memory");
        bf16x8 pf0 = *(const bf16x8*)(P + fr * 64 + fg * 8);
        bf16x8 pf1 = *(const bf16x8*)(P + fr * 64 + 32 + fg * 8);
        #pragma unroll
        for (int nf = 0; nf < 8; ++nf) {
            const bf16_t* vrow = Vb + (size_t)(nf * 16 + fr) * S_LEN + kvb;
            bf16x8 v0 = *(const bf16x8*)(vrow + fg * 8);
            bf16x8 v1 = *(const bf16x8*)(vrow + 32 + fg * 8);
            oacc[nf] = __builtin_amdgcn_mfma_f32_16x16x32_bf16(pf0, v0, oacc[nf], 0, 0, 0);
            oacc[nf] = __builtin_amdgcn_mfma_f32_16x16x32_bf16(pf1, v1, oacc[nf], 0, 0, 0);
        }
    }
    float rl[4];
    #pragma unroll
    for (int r = 0; r < 4; ++r) rl[r] = 1.0f / l_i[r];
    #pragma unroll
    for (int nf = 0; nf < 8; ++nf)
        #pragma unroll
        for (int r = 0; r < 4; ++r) {
            const int row = qbase + fg * 4 + r;
            AO[(size_t)(b * S_LEN + row) * D_MODEL + h * HEAD_DIM + nf * 16 + fr] =
                (bf16_t)(oacc[nf][r] * rl[r]);
        }
}

// ============================  launch  ============================
extern "C" void kernel_launch(void* const* d_in, const int* in_sizes, int n_in,
                              void* d_out, int out_size, void* d_ws, size_t ws_size,
                              hipStream_t stream)
{
    const float* x     = (const float*)d_in[0];
    const float* scale = (const float*)d_in[1];
    const float* w_dq  = (const float*)d_in[2];
    const float* w_uq  = (const float*)d_in[3];
    const float* w_dkv = (const float*)d_in[4];
    const float* w_ukv = (const float*)d_in[5];
    const float* w_o   = (const float*)d_in[6];
    float* out0 = (float*)d_out;                        // (4096, 3072)
    float* out1 = out0 + (size_t)NTOK * D_MODEL;        // (4096, 2112)

    if (ws_size < 187039744ull) return;                 // fail visibly if ws too small
    char* ws = (char*)d_ws;
    // layout (with aliasing; ordering on the stream keeps it safe):
    bf16_t* XN    = (bf16_t*)(ws + 0);                  // 25165824   dead after q_down
    bf16_t* WDQT  = (bf16_t*)(ws + 25165824ull);        // 9437184    dead after q_down
    bf16_t* WUQT  = (bf16_t*)(ws + 34603008ull);        // 9437184    dead after q_up
    bf16_t* WDKVT = (bf16_t*)(ws + 44040192ull);        // 12976128   dead after kv_down
    bf16_t* WUKVT = (bf16_t*)(ws + 57016320ull);        // 18874368   dead after kv_up
    bf16_t* WOB   = (bf16_t*)(ws + 75890688ull);        // 18874368
    bf16_t* QD    = (bf16_t*)(ws + 94765056ull);        // 12582912   dead after q_up
    bf16_t* KRB   = (bf16_t*)(ws + 94765056ull);        // 524288   (aliases QD, written later)
    float*  CTAB  = (float*) (ws + 95289344ull);        // 262144   (aliases QD, written later)
    float*  STAB  = (float*) (ws + 95551488ull);        // 262144
    bf16_t* Qb    = (bf16_t*)(ws + 107347968ull);       // 25165824
    bf16_t* KVNR  = (bf16_t*)(ws + 132513792ull);       // 16777216
    bf16_t* KVUP  = (bf16_t*)(ws + 149291008ull);       // 37748736
    bf16_t* VTb   = WDQT;                               // 25165824 over WDQT..WDKVT region
    bf16_t* AO    = XN;                                 // attn_out reuses XN

    // 1. RMSNorm -> xn (bf16)
    rmsnorm_kernel<<<NTOK, 256, 0, stream>>>(x, scale, XN);
    // 2. weight conversions (B^T layouts)
    transpose_conv<<<dim3(1536/32, 3072/32), dim3(32,8), 0, stream>>>(w_dq,  WDQT,  3072, 1536);
    transpose_conv<<<dim3(3072/32, 1536/32), dim3(32,8), 0, stream>>>(w_uq,  WUQT,  1536, 3072);
    transpose_conv<<<dim3(2112/32, 3072/32), dim3(32,8), 0, stream>>>(w_dkv, WDKVT, 3072, 2112);
    transpose_conv<<<dim3(4608/32, 2048/32), dim3(32,8), 0, stream>>>(w_ukv, WUKVT, 2048, 4608);
    conv_bf16<<<2048, 256, 0, stream>>>(w_o, WOB, (D_MODEL * D_MODEL) / 4);
    // 3. kv_down = xn @ w_dkv  -> out1 (fp32, output #1) + KVNR (bf16, cols<2048)
    gemm_bt<<<dim3(17, 32), 256, 0, stream>>>(XN, WDKVT, out1, KVDN, KVNR, KV_PROJ, KV_PROJ,
                                              NTOK, KVDN, D_MODEL);
    // 4. q_down = xn @ w_dq
    gemm_bt<<<dim3(12, 32), 256, 0, stream>>>(XN, WDQT, nullptr, 0, QD, Q_PROJ, Q_PROJ,
                                              NTOK, Q_PROJ, D_MODEL);
    // 5. q = q_down @ w_uq
    gemm_bt<<<dim3(24, 32), 256, 0, stream>>>(QD, WUQT, nullptr, 0, Qb, D_MODEL, D_MODEL,
                                              NTOK, D_MODEL, Q_PROJ);
    // 6-8. RoPE (tables live in QD's region -> must come after q_up)
    rope_tab<<<(S_LEN * 32 + 255) / 256, 256, 0, stream>>>(CTAB, STAB);
    rope_q_kernel<<<(NTOK * N_HEADS * 32 + 255) / 256, 256, 0, stream>>>(Qb, CTAB, STAB);
    rope_k_kernel<<<(NTOK * 32 + 255) / 256, 256, 0, stream>>>(out1, KRB, CTAB, STAB);
    // 9. kv_up = kv_no_rope @ w_ukv
    gemm_bt<<<dim3(36, 32), 256, 0, stream>>>(KVNR, WUKVT, nullptr, 0, KVUP, KVUN, KVUN,
                                              NTOK, KVUN, KV_PROJ);
    // 10. V transpose
    vt_asm<<<dim3(S_LEN/32, HEAD_DIM/32, 48), dim3(32,8), 0, stream>>>(KVUP, VTb);
    // 11. causal flash attention
    attn_fwd<<<dim3(S_LEN/64, 48), 256, 0, stream>>>(Qb, KVUP, KRB, VTb, AO);
    // 12. output = attn_out @ w_o^T -> out0 (fp32, output #0)
    gemm_bt<<<dim3(24, 32), 256, 0, stream>>>(AO, WOB, out0, D_MODEL, nullptr, 0, 0,
                                              NTOK, D_MODEL, D_MODEL);
}

// Round 2
// 721.531 us; speedup vs baseline: 1.7791x; 1.7791x over previous
//
#include <hip/hip_runtime.h>
#include <hip/hip_bf16.h>
#include <stdint.h>

using bf16_t = __bf16;
using bf16x8 = __attribute__((ext_vector_type(8))) __bf16;
using bf16x4 = __attribute__((ext_vector_type(4))) __bf16;
using f32x4  = __attribute__((ext_vector_type(4))) float;

#define D_MODEL 3072
#define N_HEADS 24
#define HEAD_DIM 128
#define Q_PROJ 1536
#define KV_PROJ 2048
#define ROPE_DIM 64
#define S_LEN 2048
#define NTOK 4096            // B*S
#define KVDN 2112            // KV_PROJ + ROPE_DIM
#define KVUN 4608            // D_MODEL + N_HEADS*ROPE_DIM

// ---- async global->LDS (16B per lane, wave-uniform LDS base) ----
__device__ __forceinline__ void async_ld16(const void* g, void* l) {
    __builtin_amdgcn_global_load_lds(
        (__attribute__((address_space(1))) uint32_t*)(uintptr_t)g,
        (__attribute__((address_space(3))) uint32_t*)(uint32_t)(uintptr_t)l,
        16, 0, 0);
}

// =====================  RMSNorm (fp32 in -> bf16 out)  =====================
__global__ __launch_bounds__(256) void rmsnorm_kernel(
    const float* __restrict__ x, const float* __restrict__ sc, bf16_t* __restrict__ xn)
{
    const int tok = blockIdx.x;
    const int t = threadIdx.x;
    const float4* xr = (const float4*)(x + (size_t)tok * D_MODEL);
    float4 a = xr[t], b = xr[t + 256], c = xr[t + 512];
    float ss = a.x*a.x + a.y*a.y + a.z*a.z + a.w*a.w
             + b.x*b.x + b.y*b.y + b.z*b.z + b.w*b.w
             + c.x*c.x + c.y*c.y + c.z*c.z + c.w*c.w;
    #pragma unroll
    for (int off = 32; off >= 1; off >>= 1) ss += __shfl_xor(ss, off);
    __shared__ float red[4];
    if ((t & 63) == 0) red[t >> 6] = ss;
    __syncthreads();
    const float inv = rsqrtf((red[0] + red[1] + red[2] + red[3]) * (1.0f / D_MODEL) + 1e-6f);
    const float4* sr = (const float4*)sc;
    float4 s0 = sr[t], s1 = sr[t + 256], s2 = sr[t + 512];
    bf16x4* xo = (bf16x4*)(xn + (size_t)tok * D_MODEL);
    bf16x4 o;
    o[0]=(bf16_t)(a.x*s0.x*inv); o[1]=(bf16_t)(a.y*s0.y*inv); o[2]=(bf16_t)(a.z*s0.z*inv); o[3]=(bf16_t)(a.w*s0.w*inv);
    xo[t] = o;
    o[0]=(bf16_t)(b.x*s1.x*inv); o[1]=(bf16_t)(b.y*s1.y*inv); o[2]=(bf16_t)(b.z*s1.z*inv); o[3]=(bf16_t)(b.w*s1.w*inv);
    xo[t + 256] = o;
    o[0]=(bf16_t)(c.x*s2.x*inv); o[1]=(bf16_t)(c.y*s2.y*inv); o[2]=(bf16_t)(c.z*s2.z*inv); o[3]=(bf16_t)(c.w*s2.w*inv);
    xo[t + 512] = o;
}

// ============  weight transpose fp32 (K x N) -> bf16 B^T (N x K)  ============
__global__ void transpose_conv(const float* __restrict__ in, bf16_t* __restrict__ out, int K, int N)
{
    __shared__ float tile[32][33];
    const int n0 = blockIdx.x * 32, k0 = blockIdx.y * 32;
    const int tx = threadIdx.x, ty = threadIdx.y;
    #pragma unroll
    for (int i = 0; i < 32; i += 8)
        tile[ty + i][tx] = in[(size_t)(k0 + ty + i) * N + n0 + tx];
    __syncthreads();
    #pragma unroll
    for (int i = 0; i < 32; i += 8)
        out[(size_t)(n0 + ty + i) * K + k0 + tx] = (bf16_t)tile[tx][ty + i];
}

// ==================  plain fp32 -> bf16 conversion (w_o)  ==================
__global__ void conv_bf16(const float* __restrict__ in, bf16_t* __restrict__ out, int n4)
{
    const int stride = gridDim.x * 256;
    for (int i = blockIdx.x * 256 + threadIdx.x; i < n4; i += stride) {
        float4 v = ((const float4*)in)[i];
        bf16x4 o;
        o[0] = (bf16_t)v.x; o[1] = (bf16_t)v.y; o[2] = (bf16_t)v.z; o[3] = (bf16_t)v.w;
        ((bf16x4*)out)[i] = o;
    }
}

// =====  GEMM: C[m,n] = sum_k A[m,k]*B[n,k];  A M x K bf16, B N x K bf16  =====
__global__ __launch_bounds__(256) void gemm_bt(
    const bf16_t* __restrict__ A, const bf16_t* __restrict__ B,
    float* __restrict__ Cf, int ldcf,
    bf16_t* __restrict__ Cb, int ldcb, int nbmax,
    int M, int N, int K)
{
    __shared__ bf16_t As[128 * 32];
    __shared__ bf16_t Bs[128 * 32];
    const int t = threadIdx.x;
    const int wave = t >> 6, lane = t & 63;
    const int m0 = blockIdx.y * 128, n0 = blockIdx.x * 128;
    const int wm = (wave >> 1) * 64, wn = (wave & 1) * 64;
    const int lrow = lane >> 2;
    const int lcol = (lane & 3) * 8;
    const int c0 = wave, c1 = wave + 4;

    const int ar0 = m0 + c0 * 16 + lrow;
    const int ar1 = m0 + c1 * 16 + lrow;
    int br0 = n0 + c0 * 16 + lrow; if (br0 > N - 1) br0 = N - 1;
    int br1 = n0 + c1 * 16 + lrow; if (br1 > N - 1) br1 = N - 1;
    const bf16_t* ap0 = A + (size_t)ar0 * K + lcol;
    const bf16_t* ap1 = A + (size_t)ar1 * K + lcol;
    const bf16_t* bp0 = B + (size_t)br0 * K + lcol;
    const bf16_t* bp1 = B + (size_t)br1 * K + lcol;
    bf16_t* lA0 = As + c0 * 512;
    bf16_t* lA1 = As + c1 * 512;
    bf16_t* lB0 = Bs + c0 * 512;
    bf16_t* lB1 = Bs + c1 * 512;

    f32x4 zero = {0.f, 0.f, 0.f, 0.f};
    f32x4 acc[4][4];
    #pragma unroll
    for (int i = 0; i < 4; ++i)
        #pragma unroll
        for (int j = 0; j < 4; ++j) acc[i][j] = zero;

    const int fr = lane & 15;
    const int fk = (lane >> 4) * 8;

    for (int k0 = 0; k0 < K; k0 += 32) {
        async_ld16(ap0 + k0, lA0);
        async_ld16(ap1 + k0, lA1);
        async_ld16(bp0 + k0, lB0);
        async_ld16(bp1 + k0, lB1);
        __syncthreads();
        bf16x8 af[4], bfv[4];
        #pragma unroll
        for (int i = 0; i < 4; ++i) af[i] = *(const bf16x8*)(As + (wm + i * 16 + fr) * 32 + fk);
        #pragma unroll
        for (int j = 0; j < 4; ++j) bfv[j] = *(const bf16x8*)(Bs + (wn + j * 16 + fr) * 32 + fk);
        #pragma unroll
        for (int i = 0; i < 4; ++i)
            #pragma unroll
            for (int j = 0; j < 4; ++j)
                acc[i][j] = __builtin_amdgcn_mfma_f32_16x16x32_bf16(af[i], bfv[j], acc[i][j], 0, 0, 0);
        __syncthreads();
    }

    const int colb = n0 + wn + fr;
    const int rowb = m0 + wm + (lane >> 4) * 4;
    #pragma unroll
    for (int i = 0; i < 4; ++i) {
        #pragma unroll
        for (int j = 0; j < 4; ++j) {
            const int col = colb + j * 16;
            #pragma unroll
            for (int r = 0; r < 4; ++r) {
                const int row = rowb + i * 16 + r;
                const float v = acc[i][j][r];
                if (Cf && col < N)     Cf[(size_t)row * ldcf + col] = v;
                if (Cb && col < nbmax) Cb[(size_t)row * ldcb + col] = (bf16_t)v;
            }
        }
    }
}

// =========================  RoPE tables (fp32)  =========================
__global__ void rope_tab(float* __restrict__ ctab, float* __restrict__ stab)
{
    const int idx = blockIdx.x * 256 + threadIdx.x;
    if (idx >= S_LEN * 32) return;
    const int s = idx >> 5, i = idx & 31;
    const float freq = powf(10000.0f, -(float)(2 * i) * (1.0f / 128.0f));
    const float ang = (float)s * freq;
    ctab[idx] = cosf(ang);
    stab[idx] = sinf(ang);
}

// =================  RoPE on Q (in-place, dims 64..127/head)  =================
__global__ void rope_q_kernel(bf16_t* __restrict__ q, const float* __restrict__ ctab,
                              const float* __restrict__ stab)
{
    const int idx = blockIdx.x * 256 + threadIdx.x;
    if (idx >= NTOK * N_HEADS * 32) return;
    const int i = idx & 31;
    const int rest = idx >> 5;
    const int h = rest % N_HEADS;
    const int tok = rest / N_HEADS;
    const int s = tok & (S_LEN - 1);
    bf16_t* p = q + (size_t)tok * D_MODEL + h * HEAD_DIM + 64;
    const float a = (float)p[i], b = (float)p[i + 32];
    const float c = ctab[s * 32 + i], sn = stab[s * 32 + i];
    p[i]      = (bf16_t)(a * c - b * sn);
    p[i + 32] = (bf16_t)(b * c + a * sn);
}

// ==========  RoPE on shared K-rope (reads kv_down fp32 output)  ==========
__global__ void rope_k_kernel(const float* __restrict__ kvd, bf16_t* __restrict__ kr,
                              const float* __restrict__ ctab, const float* __restrict__ stab)
{
    const int idx = blockIdx.x * 256 + threadIdx.x;
    if (idx >= NTOK * 32) return;
    const int i = idx & 31;
    const int tok = idx >> 5;
    const int s = tok & (S_LEN - 1);
    const float* p = kvd + (size_t)tok * KVDN + KV_PROJ;
    const float a = p[i], b = p[i + 32];
    const float c = ctab[s * 32 + i], sn = stab[s * 32 + i];
    kr[(size_t)tok * 64 + i]      = (bf16_t)(a * c - b * sn);
    kr[(size_t)tok * 64 + i + 32] = (bf16_t)(b * c + a * sn);
}

// ======  V transpose: VT[bh][d][s] = kv_up[b, s, h*192 + 64 + d]  ======
__global__ void vt_asm(const bf16_t* __restrict__ kvup, bf16_t* __restrict__ vt)
{
    __shared__ bf16_t tile[32][33];
    const int s0 = blockIdx.x * 32, d0 = blockIdx.y * 32, bh = blockIdx.z;
    const int b = bh / N_HEADS, h = bh % N_HEADS;
    const int tx = threadIdx.x, ty = threadIdx.y;
    #pragma unroll
    for (int i = 0; i < 32; i += 8)
        tile[ty + i][tx] = kvup[(size_t)(b * S_LEN + s0 + ty + i) * KVUN + h * 192 + 64 + d0 + tx];
    __syncthreads();
    #pragma unroll
    for (int i = 0; i < 32; i += 8)
        vt[((size_t)bh * HEAD_DIM + d0 + ty + i) * S_LEN + s0 + tx] = tile[tx][ty + i];
}

// =====================  causal flash attention (v2)  =====================
// Block = 128 q-rows (4 waves x 32 rows), processes q-tile pair {x, 15-x}.
// K(no-rope), K(rope), V^T staged in LDS per 64-wide KV step with XOR swizzle.
__global__ __launch_bounds__(256, 2) void attn_fwd(
    const bf16_t* __restrict__ Q, const bf16_t* __restrict__ KVUP,
    const bf16_t* __restrict__ KR, const bf16_t* __restrict__ VT,
    bf16_t* __restrict__ AO)
{
    __shared__ bf16_t Knr[64 * 64];    // [kvrow][64 no-rope dims], 16B-chunk XOR swizzled
    __shared__ bf16_t Krp[64 * 64];    // [kvrow][64 rope dims]
    __shared__ bf16_t Vls[128 * 64];   // [d][64 kv], XOR swizzled
    __shared__ bf16_t Pls[4 * 32 * 72];// per-wave P, padded stride 72

    const int bh = blockIdx.y;
    const int b = bh / N_HEADS, h = bh % N_HEADS;
    const int wave = threadIdx.x >> 6, lane = threadIdx.x & 63;
    const int fr = lane & 15, fg = lane >> 4;
    const int rx = fr & 7;

    const bf16_t* Kb  = KVUP + (size_t)b * S_LEN * KVUN + (size_t)h * 192;
    const bf16_t* KRb = KR + (size_t)b * S_LEN * 64;
    const bf16_t* Vb  = VT + (size_t)bh * HEAD_DIM * S_LEN;
    bf16_t* P = Pls + wave * (32 * 72);

    const int srow   = lane >> 3;            // row within an 8-row staging call
    const int schunk = (lane & 7) ^ srow;    // pre-swizzled 16B chunk (rule 21)
    const float l2e_isc = 0.127500625f;      // (1/sqrt(128)) * log2(e)

    f32x4 zero = {0.f, 0.f, 0.f, 0.f};

    #pragma unroll 1
    for (int tp = 0; tp < 2; ++tp) {
        const int qt = (tp == 0) ? blockIdx.x : (15 - blockIdx.x);
        const int qb = qt * 128;
        const int wrow0 = qb + wave * 32;

        bf16x8 qf[2][4];
        #pragma unroll
        for (int rf = 0; rf < 2; ++rf)
            #pragma unroll
            for (int kc = 0; kc < 4; ++kc)
                qf[rf][kc] = *(const bf16x8*)(Q + (size_t)(b * S_LEN + wrow0 + rf * 16 + fr) * D_MODEL
                                              + h * HEAD_DIM + kc * 32 + fg * 8);
        f32x4 oacc[2][8];
        float m_i[2][4], l_i[2][4];
        #pragma unroll
        for (int rf = 0; rf < 2; ++rf) {
            #pragma unroll
            for (int nf = 0; nf < 8; ++nf) oacc[rf][nf] = zero;
            #pragma unroll
            for (int r = 0; r < 4; ++r) { m_i[rf][r] = -1e30f; l_i[rf][r] = 0.f; }
        }

        const int kvend = qb + 128;
        #pragma unroll 1
        for (int kvb = 0; kvb < kvend; kvb += 64) {
            __syncthreads();   // previous step's LDS reads complete
            // ---- stage K no-rope / K rope (2 calls each) + V (4 calls) ----
            #pragma unroll
            for (int c = 0; c < 2; ++c) {
                const int r0 = wave * 16 + c * 8;
                async_ld16(Kb  + (size_t)(kvb + r0 + srow) * KVUN + schunk * 8, Knr + r0 * 64);
                async_ld16(KRb + (size_t)(kvb + r0 + srow) * 64   + schunk * 8, Krp + r0 * 64);
            }
            #pragma unroll
            for (int c = 0; c < 4; ++c) {
                const int r0 = wave * 32 + c * 8;
                async_ld16(Vb + (size_t)(r0 + srow) * S_LEN + kvb + schunk * 8, Vls + r0 * 64);
            }
            __syncthreads();   // staging visible

            if (kvb > wrow0 + 31) continue;   // this wave's rows done (barriers above still run)

            // ---- QK^T ----
            f32x4 sacc[2][4];
            #pragma unroll
            for (int rf = 0; rf < 2; ++rf)
                #pragma unroll
                for (int jn = 0; jn < 4; ++jn) sacc[rf][jn] = zero;
            #pragma unroll
            for (int jn = 0; jn < 4; ++jn) {
                const int krow = jn * 16 + fr;
                bf16x8 kA = *(const bf16x8*)(Knr + krow * 64 + (((0 + fg) ^ rx) << 3));
                bf16x8 kB = *(const bf16x8*)(Knr + krow * 64 + (((4 + fg) ^ rx) << 3));
                bf16x8 kC = *(const bf16x8*)(Krp + krow * 64 + (((0 + fg) ^ rx) << 3));
                bf16x8 kD = *(const bf16x8*)(Krp + krow * 64 + (((4 + fg) ^ rx) << 3));
                #pragma unroll
                for (int rf = 0; rf < 2; ++rf) {
                    sacc[rf][jn] = __builtin_amdgcn_mfma_f32_16x16x32_bf16(qf[rf][0], kA, sacc[rf][jn], 0, 0, 0);
                    sacc[rf][jn] = __builtin_amdgcn_mfma_f32_16x16x32_bf16(qf[rf][1], kB, sacc[rf][jn], 0, 0, 0);
                    sacc[rf][jn] = __builtin_amdgcn_mfma_f32_16x16x32_bf16(qf[rf][2], kC, sacc[rf][jn], 0, 0, 0);
                    sacc[rf][jn] = __builtin_amdgcn_mfma_f32_16x16x32_bf16(qf[rf][3], kD, sacc[rf][jn], 0, 0, 0);
                }
            }

            // ---- softmax (exp2 domain) ----
            const bool needMask = (kvb + 63 > wrow0);
            float mrow[2][4];
            #pragma unroll
            for (int rf = 0; rf < 2; ++rf)
                #pragma unroll
                for (int r = 0; r < 4; ++r) {
                    const int row = wrow0 + rf * 16 + fg * 4 + r;
                    float mx = -1e30f;
                    #pragma unroll
                    for (int jn = 0; jn < 4; ++jn) {
                        float v = sacc[rf][jn][r] * l2e_isc;
                        if (needMask && (kvb + jn * 16 + fr > row)) v = -1e30f;
                        sacc[rf][jn][r] = v;
                        mx = fmaxf(mx, v);
                    }
                    mrow[rf][r] = mx;
                }
            #pragma unroll
            for (int off = 1; off < 16; off <<= 1)
                #pragma unroll
                for (int rf = 0; rf < 2; ++rf)
                    #pragma unroll
                    for (int r = 0; r < 4; ++r)
                        mrow[rf][r] = fmaxf(mrow[rf][r], __shfl_xor(mrow[rf][r], off));
            float scf[2][4], lsum[2][4];
            #pragma unroll
            for (int rf = 0; rf < 2; ++rf)
                #pragma unroll
                for (int r = 0; r < 4; ++r) {
                    const float mn = fmaxf(m_i[rf][r], mrow[rf][r]);
                    scf[rf][r] = __builtin_amdgcn_exp2f(m_i[rf][r] - mn);
                    m_i[rf][r] = mn;
                    float s = 0.f;
                    #pragma unroll
                    for (int jn = 0; jn < 4; ++jn) {
                        const float p = __builtin_amdgcn_exp2f(sacc[rf][jn][r] - mn);
                        sacc[rf][jn][r] = p;
                        s += p;
                    }
                    lsum[rf][r] = s;
                }
            #pragma unroll
            for (int off = 1; off < 16; off <<= 1)
                #pragma unroll
                for (int rf = 0; rf < 2; ++rf)
                    #pragma unroll
                    for (int r = 0; r < 4; ++r)
                        lsum[rf][r] += __shfl_xor(lsum[rf][r], off);
            #pragma unroll
            for (int rf = 0; rf < 2; ++rf)
                #pragma unroll
                for (int r = 0; r < 4; ++r) {
                    l_i[rf][r] = l_i[rf][r] * scf[rf][r] + lsum[rf][r];
                    #pragma unroll
                    for (int nf = 0; nf < 8; ++nf) oacc[rf][nf][r] *= scf[rf][r];
                }

            // ---- P -> LDS (D layout) -> A fragments ----
            #pragma unroll
            for (int rf = 0; rf < 2; ++rf)
                #pragma unroll
                for (int jn = 0; jn < 4; ++jn)
                    #pragma unroll
                    for (int r = 0; r < 4; ++r)
                        P[(rf * 16 + fg * 4 + r) * 72 + jn * 16 + fr] = (bf16_t)sacc[rf][jn][r];
            bf16x8 pf[2][2];
            #pragma unroll
            for (int rf = 0; rf < 2; ++rf)
                #pragma unroll
                for (int c = 0; c < 2; ++c)
                    pf[rf][c] = *(const bf16x8*)(P + (rf * 16 + fr) * 72 + c * 32 + fg * 8);

            // ---- PV ----
            #pragma unroll
            for (int nf = 0; nf < 8; ++nf) {
                const int vrow = nf * 16 + fr;
                bf16x8 v0 = *(const bf16x8*)(Vls + vrow * 64 + (((0 + fg) ^ rx) << 3));
                bf16x8 v1 = *(const bf16x8*)(Vls + vrow * 64 + (((4 + fg) ^ rx) << 3));
                #pragma unroll
                for (int rf = 0; rf < 2; ++rf) {
                    oacc[rf][nf] = __builtin_amdgcn_mfma_f32_16x16x32_bf16(pf[rf][0], v0, oacc[rf][nf], 0, 0, 0);
                    oacc[rf][nf] = __builtin_amdgcn_mfma_f32_16x16x32_bf16(pf[rf][1], v1, oacc[rf][nf], 0, 0, 0);
                }
            }
        }

        // ---- epilogue: normalize + store ----
        #pragma unroll
        for (int rf = 0; rf < 2; ++rf) {
            float rl[4];
            #pragma unroll
            for (int r = 0; r < 4; ++r) rl[r] = __builtin_amdgcn_rcpf(l_i[rf][r]);
            #pragma unroll
            for (int nf = 0; nf < 8; ++nf)
                #pragma unroll
                for (int r = 0; r < 4; ++r) {
                    const int row = wrow0 + rf * 16 + fg * 4 + r;
                    AO[(size_t)(b * S_LEN + row) * D_MODEL + h * HEAD_DIM + nf * 16 + fr] =
                        (bf16_t)(oacc[rf][nf][r] * rl[r]);
                }
        }
    }
}

// ============================  launch  ============================
extern "C" void kernel_launch(void* const* d_in, const int* in_sizes, int n_in,
                              void* d_out, int out_size, void* d_ws, size_t ws_size,
                              hipStream_t stream)
{
    const float* x     = (const float*)d_in[0];
    const float* scale = (const float*)d_in[1];
    const float* w_dq  = (const float*)d_in[2];
    const float* w_uq  = (const float*)d_in[3];
    const float* w_dkv = (const float*)d_in[4];
    const float* w_ukv = (const float*)d_in[5];
    const float* w_o   = (const float*)d_in[6];
    float* out0 = (float*)d_out;                        // (4096, 3072)
    float* out1 = out0 + (size_t)NTOK * D_MODEL;        // (4096, 2112)

    if (ws_size < 187039744ull) return;
    char* ws = (char*)d_ws;
    bf16_t* XN    = (bf16_t*)(ws + 0);                  // dead after q_down/kv_down
    bf16_t* WDQT  = (bf16_t*)(ws + 25165824ull);
    bf16_t* WUQT  = (bf16_t*)(ws + 34603008ull);
    bf16_t* WDKVT = (bf16_t*)(ws + 44040192ull);
    bf16_t* WUKVT = (bf16_t*)(ws + 57016320ull);
    bf16_t* WOB   = (bf16_t*)(ws + 75890688ull);
    bf16_t* QD    = (bf16_t*)(ws + 94765056ull);
    bf16_t* KRB   = (bf16_t*)(ws + 94765056ull);        // aliases QD (written after q_up)
    float*  CTAB  = (float*) (ws + 95289344ull);
    float*  STAB  = (float*) (ws + 95551488ull);
    bf16_t* Qb    = (bf16_t*)(ws + 107347968ull);
    bf16_t* KVNR  = (bf16_t*)(ws + 132513792ull);
    bf16_t* KVUP  = (bf16_t*)(ws + 149291008ull);
    bf16_t* VTb   = WDQT;                               // reuses weight region
    bf16_t* AO    = XN;

    rmsnorm_kernel<<<NTOK, 256, 0, stream>>>(x, scale, XN);
    transpose_conv<<<dim3(1536/32, 3072/32), dim3(32,8), 0, stream>>>(w_dq,  WDQT,  3072, 1536);
    transpose_conv<<<dim3(3072/32, 1536/32), dim3(32,8), 0, stream>>>(w_uq,  WUQT,  1536, 3072);
    transpose_conv<<<dim3(2112/32, 3072/32), dim3(32,8), 0, stream>>>(w_dkv, WDKVT, 3072, 2112);
    transpose_conv<<<dim3(4608/32, 2048/32), dim3(32,8), 0, stream>>>(w_ukv, WUKVT, 2048, 4608);
    conv_bf16<<<2048, 256, 0, stream>>>(w_o, WOB, (D_MODEL * D_MODEL) / 4);
    gemm_bt<<<dim3(17, 32), 256, 0, stream>>>(XN, WDKVT, out1, KVDN, KVNR, KV_PROJ, KV_PROJ,
                                              NTOK, KVDN, D_MODEL);
    gemm_bt<<<dim3(12, 32), 256, 0, stream>>>(XN, WDQT, nullptr, 0, QD, Q_PROJ, Q_PROJ,
                                              NTOK, Q_PROJ, D_MODEL);
    gemm_bt<<<dim3(24, 32), 256, 0, stream>>>(QD, WUQT, nullptr, 0, Qb, D_MODEL, D_MODEL,
                                              NTOK, D_MODEL, Q_PROJ);
    rope_tab<<<(S_LEN * 32 + 255) / 256, 256, 0, stream>>>(CTAB, STAB);
    rope_q_kernel<<<(NTOK * N_HEADS * 32 + 255) / 256, 256, 0, stream>>>(Qb, CTAB, STAB);
    rope_k_kernel<<<(NTOK * 32 + 255) / 256, 256, 0, stream>>>(out1, KRB, CTAB, STAB);
    gemm_bt<<<dim3(36, 32), 256, 0, stream>>>(KVNR, WUKVT, nullptr, 0, KVUP, KVUN, KVUN,
                                              NTOK, KVUN, KV_PROJ);
    vt_asm<<<dim3(S_LEN/32, HEAD_DIM/32, 48), dim3(32,8), 0, stream>>>(KVUP, VTb);
    attn_fwd<<<dim3(8, 48), 256, 0, stream>>>(Qb, KVUP, KRB, VTb, AO);
    gemm_bt<<<dim3(24, 32), 256, 0, stream>>>(AO, WOB, out0, D_MODEL, nullptr, 0, 0,
                                              NTOK, D_MODEL, D_MODEL);
}

// Round 3
// 590.834 us; speedup vs baseline: 2.1727x; 1.2212x over previous
//
#include <hip/hip_runtime.h>
#include <hip/hip_bf16.h>
#include <stdint.h>

using bf16_t = __bf16;
using bf16x8 = __attribute__((ext_vector_type(8))) __bf16;
using bf16x4 = __attribute__((ext_vector_type(4))) __bf16;
using f32x4  = __attribute__((ext_vector_type(4))) float;

#define D_MODEL 3072
#define N_HEADS 24
#define HEAD_DIM 128
#define Q_PROJ 1536
#define KV_PROJ 2048
#define ROPE_DIM 64
#define S_LEN 2048
#define NTOK 4096            // B*S
#define KVDN 2112            // KV_PROJ + ROPE_DIM
#define KVUN 4608            // D_MODEL + N_HEADS*ROPE_DIM

// ---- async global->LDS (16B per lane, wave-uniform LDS base) ----
__device__ __forceinline__ void async_ld16(const void* g, void* l) {
    __builtin_amdgcn_global_load_lds(
        (__attribute__((address_space(1))) uint32_t*)(uintptr_t)g,
        (__attribute__((address_space(3))) uint32_t*)(uint32_t)(uintptr_t)l,
        16, 0, 0);
}

#define BARRIER() __builtin_amdgcn_s_barrier()
#define WAITV4() asm volatile("s_waitcnt vmcnt(4)" ::: "memory")
#define WAITV0() asm volatile("s_waitcnt vmcnt(0)" ::: "memory")

// =====================  RMSNorm (fp32 in -> bf16 out)  =====================
__global__ __launch_bounds__(256) void rmsnorm_kernel(
    const float* __restrict__ x, const float* __restrict__ sc, bf16_t* __restrict__ xn)
{
    const int tok = blockIdx.x;
    const int t = threadIdx.x;
    const float4* xr = (const float4*)(x + (size_t)tok * D_MODEL);
    float4 a = xr[t], b = xr[t + 256], c = xr[t + 512];
    float ss = a.x*a.x + a.y*a.y + a.z*a.z + a.w*a.w
             + b.x*b.x + b.y*b.y + b.z*b.z + b.w*b.w
             + c.x*c.x + c.y*c.y + c.z*c.z + c.w*c.w;
    #pragma unroll
    for (int off = 32; off >= 1; off >>= 1) ss += __shfl_xor(ss, off);
    __shared__ float red[4];
    if ((t & 63) == 0) red[t >> 6] = ss;
    __syncthreads();
    const float inv = rsqrtf((red[0] + red[1] + red[2] + red[3]) * (1.0f / D_MODEL) + 1e-6f);
    const float4* sr = (const float4*)sc;
    float4 s0 = sr[t], s1 = sr[t + 256], s2 = sr[t + 512];
    bf16x4* xo = (bf16x4*)(xn + (size_t)tok * D_MODEL);
    bf16x4 o;
    o[0]=(bf16_t)(a.x*s0.x*inv); o[1]=(bf16_t)(a.y*s0.y*inv); o[2]=(bf16_t)(a.z*s0.z*inv); o[3]=(bf16_t)(a.w*s0.w*inv);
    xo[t] = o;
    o[0]=(bf16_t)(b.x*s1.x*inv); o[1]=(bf16_t)(b.y*s1.y*inv); o[2]=(bf16_t)(b.z*s1.z*inv); o[3]=(bf16_t)(b.w*s1.w*inv);
    xo[t + 256] = o;
    o[0]=(bf16_t)(c.x*s2.x*inv); o[1]=(bf16_t)(c.y*s2.y*inv); o[2]=(bf16_t)(c.z*s2.z*inv); o[3]=(bf16_t)(c.w*s2.w*inv);
    xo[t + 512] = o;
}

// ============  weight transpose fp32 (K x N) -> bf16 B^T (N x K)  ============
__global__ void transpose_conv(const float* __restrict__ in, bf16_t* __restrict__ out, int K, int N)
{
    __shared__ float tile[32][33];
    const int n0 = blockIdx.x * 32, k0 = blockIdx.y * 32;
    const int tx = threadIdx.x, ty = threadIdx.y;
    #pragma unroll
    for (int i = 0; i < 32; i += 8)
        tile[ty + i][tx] = in[(size_t)(k0 + ty + i) * N + n0 + tx];
    __syncthreads();
    #pragma unroll
    for (int i = 0; i < 32; i += 8)
        out[(size_t)(n0 + ty + i) * K + k0 + tx] = (bf16_t)tile[tx][ty + i];
}

// ==================  plain fp32 -> bf16 conversion (w_o)  ==================
__global__ void conv_bf16(const float* __restrict__ in, bf16_t* __restrict__ out, int n4)
{
    const int stride = gridDim.x * 256;
    for (int i = blockIdx.x * 256 + threadIdx.x; i < n4; i += stride) {
        float4 v = ((const float4*)in)[i];
        bf16x4 o;
        o[0] = (bf16_t)v.x; o[1] = (bf16_t)v.y; o[2] = (bf16_t)v.z; o[3] = (bf16_t)v.w;
        ((bf16x4*)out)[i] = o;
    }
}

// ==========================  256x256 8-phase GEMM  ==========================
// C[m,n] = sum_k A[m,k] * B[n,k].  M=4096 (grid.y=16), BN=256 tiles (grid.x),
// BK=64 in two 32-wide half-units. 512 thr = 8 waves (2x4), 128x64 out/wave.
// LDS: A-ring 4x16KB @0, B-ring 4x16KB @64KB; unit (t,kh) -> slot (2t+kh)&3.
// Stage 1 unit/phase (2x global_load_lds w16/thread), vmcnt(4) at p4/p8 only.
// XOR swizzle both sides: 16B-chunk c within unit: c ^= (c>>3)&3 (involution).
template<int CFP>
__device__ __forceinline__ void mfma16(f32x4 (&acc)[8][4], const bf16x8 (&af)[8],
                                       const bf16x8 (&bfv)[2]) {
    __builtin_amdgcn_s_setprio(1);
    #pragma unroll
    for (int rf = 0; rf < 8; ++rf) {
        acc[rf][2*CFP]   = __builtin_amdgcn_mfma_f32_16x16x32_bf16(af[rf], bfv[0], acc[rf][2*CFP],   0, 0, 0);
        acc[rf][2*CFP+1] = __builtin_amdgcn_mfma_f32_16x16x32_bf16(af[rf], bfv[1], acc[rf][2*CFP+1], 0, 0, 0);
    }
    __builtin_amdgcn_s_setprio(0);
}

__global__ __launch_bounds__(512, 2) void gemm256(
    const bf16_t* __restrict__ A, const bf16_t* __restrict__ B, int N, int K,
    float* __restrict__ Cf, int ldf, int flo, int fhi,
    bf16_t* __restrict__ Cb1, int ldb1, int b1lo, int b1hi,
    bf16_t* __restrict__ Cb2, int ldb2, int b2lo, int b2hi)
{
    __shared__ char LDS[131072];
    char* Lc = LDS;
    const int tid = threadIdx.x;
    const int wv = tid >> 6, lane = tid & 63;
    const int fr = lane & 15, fg = lane >> 4;
    const int wr = wv >> 2, wc = wv & 3;                  // 2 x 4 wave grid
    const int m0 = blockIdx.y << 8, n0 = blockIdx.x << 8;
    const uint32_t slot4 = (uint32_t)((fg ^ ((fr >> 1) & 3)) << 4);  // swizzled 16B slot

    // ---- staging precompute: j-th load of a 16KB unit, chunk c = j*512+tid ----
    int grow[2], gcol[2];
    const bf16_t* agp[2]; const bf16_t* bgp[2];
    uint32_t aoff[2], boff[2];
    #pragma unroll
    for (int j = 0; j < 2; ++j) {
        const int c = j * 512 + tid;
        const int g = c ^ ((c >> 3) & 3);                 // pre-swizzled source chunk
        grow[j] = g >> 2; gcol[j] = g & 3;
        agp[j] = A + (size_t)(m0 + grow[j]) * K + gcol[j] * 8;
        int br = n0 + grow[j]; if (br > N - 1) br = N - 1;
        bgp[j] = B + (size_t)br * K + gcol[j] * 8;
        aoff[j] = (uint32_t)((j * 8 + wv) * 1024);        // wave-uniform LDS byte base
        boff[j] = (uint32_t)(65536 + (j * 8 + wv) * 1024);
    }

    f32x4 acc[8][4];
    f32x4 zero = {0.f, 0.f, 0.f, 0.f};
    #pragma unroll
    for (int i = 0; i < 8; ++i)
        #pragma unroll
        for (int j = 0; j < 4; ++j) acc[i][j] = zero;

    bf16x8 af[8], bfv[2];
    const int rowA = (wr << 7) + fr;                      // + rf*16 per fragment
    const int rowB = (wc << 6) + fr;                      // + cf*16

    // stage helpers (t, kh runtime-uniform)
    auto stA = [&](int t, int kh) {
        const uint32_t sb = (uint32_t)(((2*t + kh) & 3) << 14);
        #pragma unroll
        for (int j = 0; j < 2; ++j)
            async_ld16(agp[j] + t * 64 + kh * 32, Lc + sb + aoff[j]);
    };
    auto stB = [&](int t, int kh) {
        const uint32_t sb = (uint32_t)(((2*t + kh) & 3) << 14);
        #pragma unroll
        for (int j = 0; j < 2; ++j)
            async_ld16(bgp[j] + t * 64 + kh * 32, Lc + sb + boff[j]);
    };
    auto ldA8 = [&](int t, int kh) {
        const uint32_t base = (uint32_t)(((2*t + kh) & 3) << 14);
        #pragma unroll
        for (int rf = 0; rf < 8; ++rf)
            af[rf] = *(const bf16x8*)(Lc + base + (rowA + rf * 16) * 64 + slot4);
    };
    auto ldB2 = [&](int t, int kh, int cfp) {
        const uint32_t base = (uint32_t)(65536 + (((2*t + kh) & 3) << 14));
        #pragma unroll
        for (int c = 0; c < 2; ++c)
            bfv[c] = *(const bf16x8*)(Lc + base + (rowB + (cfp * 2 + c) * 16) * 64 + slot4);
    };

    const int NT = K >> 6, nIter = NT >> 1;
    // ---- prologue: tile0 (4 units) + tile1 k0 (2 units); drain tile0 ----
    stA(0, 0); stB(0, 0); stA(0, 1); stB(0, 1); stA(1, 0); stB(1, 0);
    WAITV4(); BARRIER();

    for (int i = 0; i < nIter; ++i) {
        const int t0 = 2 * i, t1 = t0 + 1, t2 = t0 + 2, t3 = t0 + 3;
        const bool pref = (i < nIter - 1);
        // p1
        ldA8(t0, 0); ldB2(t0, 0, 0); stA(t1, 1);
        BARRIER(); mfma16<0>(acc, af, bfv); BARRIER();
        // p2
        ldB2(t0, 0, 1); stB(t1, 1);
        BARRIER(); mfma16<1>(acc, af, bfv); BARRIER();
        // p3
        ldA8(t0, 1); ldB2(t0, 1, 0); if (pref) stA(t2, 0);
        BARRIER(); mfma16<0>(acc, af, bfv); BARRIER();
        // p4
        ldB2(t0, 1, 1); if (pref) stB(t2, 0);
        if (pref) { WAITV4(); } else { WAITV0(); }
        BARRIER(); mfma16<1>(acc, af, bfv); BARRIER();
        // p5
        ldA8(t1, 0); ldB2(t1, 0, 0); if (pref) stA(t2, 1);
        BARRIER(); mfma16<0>(acc, af, bfv); BARRIER();
        // p6
        ldB2(t1, 0, 1); if (pref) stB(t2, 1);
        BARRIER(); mfma16<1>(acc, af, bfv); BARRIER();
        // p7
        ldA8(t1, 1); ldB2(t1, 1, 0); if (pref) stA(t3, 0);
        BARRIER(); mfma16<0>(acc, af, bfv); BARRIER();
        // p8
        ldB2(t1, 1, 1); if (pref) stB(t3, 0);
        WAITV4();
        BARRIER(); mfma16<1>(acc, af, bfv); BARRIER();
    }

    // ---- epilogue ----
    const int colb = n0 + (wc << 6) + fr;
    const int rowb = m0 + (wr << 7) + fg * 4;
    #pragma unroll
    for (int rf = 0; rf < 8; ++rf)
        #pragma unroll
        for (int cf = 0; cf < 4; ++cf) {
            const int col = colb + cf * 16;
            #pragma unroll
            for (int r = 0; r < 4; ++r) {
                const int row = rowb + rf * 16 + r;
                const float v = acc[rf][cf][r];
                if (Cf  && col >= flo  && col < fhi)  Cf [(size_t)row * ldf  + col - flo]  = v;
                if (Cb1 && col >= b1lo && col < b1hi) Cb1[(size_t)row * ldb1 + col - b1lo] = (bf16_t)v;
                if (Cb2 && col >= b2lo && col < b2hi) Cb2[(size_t)row * ldb2 + col - b2lo] = (bf16_t)v;
            }
        }
}

// =========================  RoPE tables (fp32)  =========================
__global__ void rope_tab(float* __restrict__ ctab, float* __restrict__ stab)
{
    const int idx = blockIdx.x * 256 + threadIdx.x;
    if (idx >= S_LEN * 32) return;
    const int s = idx >> 5, i = idx & 31;
    const float freq = powf(10000.0f, -(float)(2 * i) * (1.0f / 128.0f));
    const float ang = (float)s * freq;
    ctab[idx] = cosf(ang);
    stab[idx] = sinf(ang);
}

// =================  RoPE on Q (in-place, dims 64..127/head)  =================
__global__ void rope_q_kernel(bf16_t* __restrict__ q, const float* __restrict__ ctab,
                              const float* __restrict__ stab)
{
    const int idx = blockIdx.x * 256 + threadIdx.x;
    if (idx >= NTOK * N_HEADS * 32) return;
    const int i = idx & 31;
    const int rest = idx >> 5;
    const int h = rest % N_HEADS;
    const int tok = rest / N_HEADS;
    const int s = tok & (S_LEN - 1);
    bf16_t* p = q + (size_t)tok * D_MODEL + h * HEAD_DIM + 64;
    const float a = (float)p[i], b = (float)p[i + 32];
    const float c = ctab[s * 32 + i], sn = stab[s * 32 + i];
    p[i]      = (bf16_t)(a * c - b * sn);
    p[i + 32] = (bf16_t)(b * c + a * sn);
}

// ==========  RoPE on shared K-rope (reads kv_down fp32 output)  ==========
__global__ void rope_k_kernel(const float* __restrict__ kvd, bf16_t* __restrict__ kr,
                              const float* __restrict__ ctab, const float* __restrict__ stab)
{
    const int idx = blockIdx.x * 256 + threadIdx.x;
    if (idx >= NTOK * 32) return;
    const int i = idx & 31;
    const int tok = idx >> 5;
    const int s = tok & (S_LEN - 1);
    const float* p = kvd + (size_t)tok * KVDN + KV_PROJ;
    const float a = p[i], b = p[i + 32];
    const float c = ctab[s * 32 + i], sn = stab[s * 32 + i];
    kr[(size_t)tok * 64 + i]      = (bf16_t)(a * c - b * sn);
    kr[(size_t)tok * 64 + i + 32] = (bf16_t)(b * c + a * sn);
}

// ======  V transpose: VT[bh][d][s] = kv_up[b, s, h*192 + 64 + d]  ======
__global__ void vt_asm(const bf16_t* __restrict__ kvup, bf16_t* __restrict__ vt)
{
    __shared__ bf16_t tile[32][33];
    const int s0 = blockIdx.x * 32, d0 = blockIdx.y * 32, bh = blockIdx.z;
    const int b = bh / N_HEADS, h = bh % N_HEADS;
    const int tx = threadIdx.x, ty = threadIdx.y;
    #pragma unroll
    for (int i = 0; i < 32; i += 8)
        tile[ty + i][tx] = kvup[(size_t)(b * S_LEN + s0 + ty + i) * KVUN + h * 192 + 64 + d0 + tx];
    __syncthreads();
    #pragma unroll
    for (int i = 0; i < 32; i += 8)
        vt[((size_t)bh * HEAD_DIM + d0 + ty + i) * S_LEN + s0 + tx] = tile[tx][ty + i];
}

// =====================  causal flash attention  =====================
__global__ __launch_bounds__(256, 2) void attn_fwd(
    const bf16_t* __restrict__ Q, const bf16_t* __restrict__ KVUP,
    const bf16_t* __restrict__ KR, const bf16_t* __restrict__ VT,
    bf16_t* __restrict__ AO)
{
    __shared__ bf16_t Knr[64 * 64];
    __shared__ bf16_t Krp[64 * 64];
    __shared__ bf16_t Vls[128 * 64];
    __shared__ bf16_t Pls[4 * 32 * 72];

    const int bh = blockIdx.y;
    const int b = bh / N_HEADS, h = bh % N_HEADS;
    const int wave = threadIdx.x >> 6, lane = threadIdx.x & 63;
    const int fr = lane & 15, fg = lane >> 4;
    const int rx = fr & 7;

    const bf16_t* Kb  = KVUP + (size_t)b * S_LEN * KVUN + (size_t)h * 192;
    const bf16_t* KRb = KR + (size_t)b * S_LEN * 64;
    const bf16_t* Vb  = VT + (size_t)bh * HEAD_DIM * S_LEN;
    bf16_t* P = Pls + wave * (32 * 72);

    const int srow   = lane >> 3;
    const int schunk = (lane & 7) ^ srow;
    const float l2e_isc = 0.127500625f;      // (1/sqrt(128)) * log2(e)

    f32x4 zero = {0.f, 0.f, 0.f, 0.f};

    #pragma unroll 1
    for (int tp = 0; tp < 2; ++tp) {
        const int qt = (tp == 0) ? blockIdx.x : (15 - blockIdx.x);
        const int qb = qt * 128;
        const int wrow0 = qb + wave * 32;

        bf16x8 qf[2][4];
        #pragma unroll
        for (int rf = 0; rf < 2; ++rf)
            #pragma unroll
            for (int kc = 0; kc < 4; ++kc)
                qf[rf][kc] = *(const bf16x8*)(Q + (size_t)(b * S_LEN + wrow0 + rf * 16 + fr) * D_MODEL
                                              + h * HEAD_DIM + kc * 32 + fg * 8);
        f32x4 oacc[2][8];
        float m_i[2][4], l_i[2][4];
        #pragma unroll
        for (int rf = 0; rf < 2; ++rf) {
            #pragma unroll
            for (int nf = 0; nf < 8; ++nf) oacc[rf][nf] = zero;
            #pragma unroll
            for (int r = 0; r < 4; ++r) { m_i[rf][r] = -1e30f; l_i[rf][r] = 0.f; }
        }

        const int kvend = qb + 128;
        #pragma unroll 1
        for (int kvb = 0; kvb < kvend; kvb += 64) {
            __syncthreads();
            #pragma unroll
            for (int c = 0; c < 2; ++c) {
                const int r0 = wave * 16 + c * 8;
                async_ld16(Kb  + (size_t)(kvb + r0 + srow) * KVUN + schunk * 8, Knr + r0 * 64);
                async_ld16(KRb + (size_t)(kvb + r0 + srow) * 64   + schunk * 8, Krp + r0 * 64);
            }
            #pragma unroll
            for (int c = 0; c < 4; ++c) {
                const int r0 = wave * 32 + c * 8;
                async_ld16(Vb + (size_t)(r0 + srow) * S_LEN + kvb + schunk * 8, Vls + r0 * 64);
            }
            __syncthreads();

            if (kvb > wrow0 + 31) continue;

            f32x4 sacc[2][4];
            #pragma unroll
            for (int rf = 0; rf < 2; ++rf)
                #pragma unroll
                for (int jn = 0; jn < 4; ++jn) sacc[rf][jn] = zero;
            #pragma unroll
            for (int jn = 0; jn < 4; ++jn) {
                const int krow = jn * 16 + fr;
                bf16x8 kA = *(const bf16x8*)(Knr + krow * 64 + (((0 + fg) ^ rx) << 3));
                bf16x8 kB = *(const bf16x8*)(Knr + krow * 64 + (((4 + fg) ^ rx) << 3));
                bf16x8 kC = *(const bf16x8*)(Krp + krow * 64 + (((0 + fg) ^ rx) << 3));
                bf16x8 kD = *(const bf16x8*)(Krp + krow * 64 + (((4 + fg) ^ rx) << 3));
                #pragma unroll
                for (int rf = 0; rf < 2; ++rf) {
                    sacc[rf][jn] = __builtin_amdgcn_mfma_f32_16x16x32_bf16(qf[rf][0], kA, sacc[rf][jn], 0, 0, 0);
                    sacc[rf][jn] = __builtin_amdgcn_mfma_f32_16x16x32_bf16(qf[rf][1], kB, sacc[rf][jn], 0, 0, 0);
                    sacc[rf][jn] = __builtin_amdgcn_mfma_f32_16x16x32_bf16(qf[rf][2], kC, sacc[rf][jn], 0, 0, 0);
                    sacc[rf][jn] = __builtin_amdgcn_mfma_f32_16x16x32_bf16(qf[rf][3], kD, sacc[rf][jn], 0, 0, 0);
                }
            }

            const bool needMask = (kvb + 63 > wrow0);
            float mrow[2][4];
            #pragma unroll
            for (int rf = 0; rf < 2; ++rf)
                #pragma unroll
                for (int r = 0; r < 4; ++r) {
                    const int row = wrow0 + rf * 16 + fg * 4 + r;
                    float mx = -1e30f;
                    #pragma unroll
                    for (int jn = 0; jn < 4; ++jn) {
                        float v = sacc[rf][jn][r] * l2e_isc;
                        if (needMask && (kvb + jn * 16 + fr > row)) v = -1e30f;
                        sacc[rf][jn][r] = v;
                        mx = fmaxf(mx, v);
                    }
                    mrow[rf][r] = mx;
                }
            #pragma unroll
            for (int off = 1; off < 16; off <<= 1)
                #pragma unroll
                for (int rf = 0; rf < 2; ++rf)
                    #pragma unroll
                    for (int r = 0; r < 4; ++r)
                        mrow[rf][r] = fmaxf(mrow[rf][r], __shfl_xor(mrow[rf][r], off));
            float scf[2][4], lsum[2][4];
            #pragma unroll
            for (int rf = 0; rf < 2; ++rf)
                #pragma unroll
                for (int r = 0; r < 4; ++r) {
                    const float mn = fmaxf(m_i[rf][r], mrow[rf][r]);
                    scf[rf][r] = __builtin_amdgcn_exp2f(m_i[rf][r] - mn);
                    m_i[rf][r] = mn;
                    float s = 0.f;
                    #pragma unroll
                    for (int jn = 0; jn < 4; ++jn) {
                        const float p = __builtin_amdgcn_exp2f(sacc[rf][jn][r] - mn);
                        sacc[rf][jn][r] = p;
                        s += p;
                    }
                    lsum[rf][r] = s;
                }
            #pragma unroll
            for (int off = 1; off < 16; off <<= 1)
                #pragma unroll
                for (int rf = 0; rf < 2; ++rf)
                    #pragma unroll
                    for (int r = 0; r < 4; ++r)
                        lsum[rf][r] += __shfl_xor(lsum[rf][r], off);
            #pragma unroll
            for (int rf = 0; rf < 2; ++rf)
                #pragma unroll
                for (int r = 0; r < 4; ++r) {
                    l_i[rf][r] = l_i[rf][r] * scf[rf][r] + lsum[rf][r];
                    #pragma unroll
                    for (int nf = 0; nf < 8; ++nf) oacc[rf][nf][r] *= scf[rf][r];
                }

            #pragma unroll
            for (int rf = 0; rf < 2; ++rf)
                #pragma unroll
                for (int jn = 0; jn < 4; ++jn)
                    #pragma unroll
                    for (int r = 0; r < 4; ++r)
                        P[(rf * 16 + fg * 4 + r) * 72 + jn * 16 + fr] = (bf16_t)sacc[rf][jn][r];
            bf16x8 pf[2][2];
            #pragma unroll
            for (int rf = 0; rf < 2; ++rf)
                #pragma unroll
                for (int c = 0; c < 2; ++c)
                    pf[rf][c] = *(const bf16x8*)(P + (rf * 16 + fr) * 72 + c * 32 + fg * 8);

            #pragma unroll
            for (int nf = 0; nf < 8; ++nf) {
                const int vrow = nf * 16 + fr;
                bf16x8 v0 = *(const bf16x8*)(Vls + vrow * 64 + (((0 + fg) ^ rx) << 3));
                bf16x8 v1 = *(const bf16x8*)(Vls + vrow * 64 + (((4 + fg) ^ rx) << 3));
                #pragma unroll
                for (int rf = 0; rf < 2; ++rf) {
                    oacc[rf][nf] = __builtin_amdgcn_mfma_f32_16x16x32_bf16(pf[rf][0], v0, oacc[rf][nf], 0, 0, 0);
                    oacc[rf][nf] = __builtin_amdgcn_mfma_f32_16x16x32_bf16(pf[rf][1], v1, oacc[rf][nf], 0, 0, 0);
                }
            }
        }

        #pragma unroll
        for (int rf = 0; rf < 2; ++rf) {
            float rl[4];
            #pragma unroll
            for (int r = 0; r < 4; ++r) rl[r] = __builtin_amdgcn_rcpf(l_i[rf][r]);
            #pragma unroll
            for (int nf = 0; nf < 8; ++nf)
                #pragma unroll
                for (int r = 0; r < 4; ++r) {
                    const int row = wrow0 + rf * 16 + fg * 4 + r;
                    AO[(size_t)(b * S_LEN + row) * D_MODEL + h * HEAD_DIM + nf * 16 + fr] =
                        (bf16_t)(oacc[rf][nf][r] * rl[r]);
                }
        }
    }
}

// ============================  launch  ============================
extern "C" void kernel_launch(void* const* d_in, const int* in_sizes, int n_in,
                              void* d_out, int out_size, void* d_ws, size_t ws_size,
                              hipStream_t stream)
{
    const float* x     = (const float*)d_in[0];
    const float* scale = (const float*)d_in[1];
    const float* w_dq  = (const float*)d_in[2];
    const float* w_uq  = (const float*)d_in[3];
    const float* w_dkv = (const float*)d_in[4];
    const float* w_ukv = (const float*)d_in[5];
    const float* w_o   = (const float*)d_in[6];
    float* out0 = (float*)d_out;                        // (4096, 3072)
    float* out1 = out0 + (size_t)NTOK * D_MODEL;        // (4096, 2112)

    if (ws_size < 187039744ull) return;
    char* ws = (char*)d_ws;
    bf16_t* XN    = (bf16_t*)(ws + 0);                  // 25165824; dead after fused down-proj
    bf16_t* WCAT  = (bf16_t*)(ws + 25165824ull);        // 22413312 = [3648][3072] b^T (dq|dkv)
    bf16_t* WUQT  = (bf16_t*)(ws + 47579136ull);        // 9437184
    bf16_t* WUKVT = (bf16_t*)(ws + 57016320ull);        // 18874368
    bf16_t* WOB   = (bf16_t*)(ws + 75890688ull);        // 18874368
    bf16_t* QD    = (bf16_t*)(ws + 94765056ull);        // 12582912; dead after q_up
    bf16_t* Qb    = (bf16_t*)(ws + 107347968ull);       // 25165824
    bf16_t* KVNR  = (bf16_t*)(ws + 132513792ull);       // 16777216
    bf16_t* KVUP  = (bf16_t*)(ws + 149291008ull);       // 37748736
    bf16_t* KRB   = (bf16_t*)(ws + 94765056ull);        // aliases QD (after q_up)
    float*  CTAB  = (float*) (ws + 95289344ull);        // in QD region (after q_up)
    float*  STAB  = (float*) (ws + 95551488ull);
    bf16_t* VTb   = WCAT;                               // reuses WCAT+WUQT region (after kv_up)
    bf16_t* AO    = XN;

    rmsnorm_kernel<<<NTOK, 256, 0, stream>>>(x, scale, XN);
    transpose_conv<<<dim3(1536/32, 3072/32), dim3(32,8), 0, stream>>>(w_dq,  WCAT, 3072, 1536);
    transpose_conv<<<dim3(2112/32, 3072/32), dim3(32,8), 0, stream>>>(w_dkv, WCAT + (size_t)1536*3072, 3072, 2112);
    transpose_conv<<<dim3(3072/32, 1536/32), dim3(32,8), 0, stream>>>(w_uq,  WUQT, 1536, 3072);
    transpose_conv<<<dim3(4608/32, 2048/32), dim3(32,8), 0, stream>>>(w_ukv, WUKVT, 2048, 4608);
    conv_bf16<<<2048, 256, 0, stream>>>(w_o, WOB, (D_MODEL * D_MODEL) / 4);

    // fused down-proj: N = 1536 (q) + 2112 (kv) = 3648
    gemm256<<<dim3(15, 16), 512, 0, stream>>>(XN, WCAT, 3648, 3072,
        out1, KVDN, 1536, 3648,            // fp32 kv_down (output #1)
        QD,   Q_PROJ, 0, 1536,             // bf16 q_down
        KVNR, KV_PROJ, 1536, 3584);        // bf16 kv_no_rope
    // q = q_down @ w_uq
    gemm256<<<dim3(12, 16), 512, 0, stream>>>(QD, WUQT, 3072, 1536,
        nullptr, 0, 0, 0, Qb, D_MODEL, 0, 3072, nullptr, 0, 0, 0);
    rope_tab<<<(S_LEN * 32 + 255) / 256, 256, 0, stream>>>(CTAB, STAB);
    rope_q_kernel<<<(NTOK * N_HEADS * 32 + 255) / 256, 256, 0, stream>>>(Qb, CTAB, STAB);
    rope_k_kernel<<<(NTOK * 32 + 255) / 256, 256, 0, stream>>>(out1, KRB, CTAB, STAB);
    // kv_up
    gemm256<<<dim3(18, 16), 512, 0, stream>>>(KVNR, WUKVT, 4608, 2048,
        nullptr, 0, 0, 0, KVUP, KVUN, 0, 4608, nullptr, 0, 0, 0);
    vt_asm<<<dim3(S_LEN/32, HEAD_DIM/32, 48), dim3(32,8), 0, stream>>>(KVUP, VTb);
    attn_fwd<<<dim3(8, 48), 256, 0, stream>>>(Qb, KVUP, KRB, VTb, AO);
    // output projection
    gemm256<<<dim3(12, 16), 512, 0, stream>>>(AO, WOB, 3072, 3072,
        out0, D_MODEL, 0, 3072, nullptr, 0, 0, 0, nullptr, 0, 0, 0);
}

// Round 4
// 555.209 us; speedup vs baseline: 2.3121x; 1.0642x over previous
//
#include <hip/hip_runtime.h>
#include <hip/hip_bf16.h>
#include <stdint.h>

using bf16_t = __bf16;
using bf16x8 = __attribute__((ext_vector_type(8))) __bf16;
using bf16x4 = __attribute__((ext_vector_type(4))) __bf16;
using f32x4  = __attribute__((ext_vector_type(4))) float;

#define D_MODEL 3072
#define N_HEADS 24
#define HEAD_DIM 128
#define Q_PROJ 1536
#define KV_PROJ 2048
#define ROPE_DIM 64
#define S_LEN 2048
#define NTOK 4096            // B*S
#define KVDN 2112            // KV_PROJ + ROPE_DIM
#define KVUN 4608            // D_MODEL + N_HEADS*ROPE_DIM

// ---- async global->LDS (16B per lane, wave-uniform LDS base) ----
__device__ __forceinline__ void async_ld16(const void* g, void* l) {
    __builtin_amdgcn_global_load_lds(
        (__attribute__((address_space(1))) uint32_t*)(uintptr_t)g,
        (__attribute__((address_space(3))) uint32_t*)(uint32_t)(uintptr_t)l,
        16, 0, 0);
}

#define BARRIER() __builtin_amdgcn_s_barrier()
#define WAITV4() asm volatile("s_waitcnt vmcnt(4)" ::: "memory")
#define WAITV0() asm volatile("s_waitcnt vmcnt(0)" ::: "memory")

// =====================  RMSNorm (fp32 in -> bf16 out)  =====================
__global__ __launch_bounds__(256) void rmsnorm_kernel(
    const float* __restrict__ x, const float* __restrict__ sc, bf16_t* __restrict__ xn)
{
    const int tok = blockIdx.x;
    const int t = threadIdx.x;
    const float4* xr = (const float4*)(x + (size_t)tok * D_MODEL);
    float4 a = xr[t], b = xr[t + 256], c = xr[t + 512];
    float ss = a.x*a.x + a.y*a.y + a.z*a.z + a.w*a.w
             + b.x*b.x + b.y*b.y + b.z*b.z + b.w*b.w
             + c.x*c.x + c.y*c.y + c.z*c.z + c.w*c.w;
    #pragma unroll
    for (int off = 32; off >= 1; off >>= 1) ss += __shfl_xor(ss, off);
    __shared__ float red[4];
    if ((t & 63) == 0) red[t >> 6] = ss;
    __syncthreads();
    const float inv = rsqrtf((red[0] + red[1] + red[2] + red[3]) * (1.0f / D_MODEL) + 1e-6f);
    const float4* sr = (const float4*)sc;
    float4 s0 = sr[t], s1 = sr[t + 256], s2 = sr[t + 512];
    bf16x4* xo = (bf16x4*)(xn + (size_t)tok * D_MODEL);
    bf16x4 o;
    o[0]=(bf16_t)(a.x*s0.x*inv); o[1]=(bf16_t)(a.y*s0.y*inv); o[2]=(bf16_t)(a.z*s0.z*inv); o[3]=(bf16_t)(a.w*s0.w*inv);
    xo[t] = o;
    o[0]=(bf16_t)(b.x*s1.x*inv); o[1]=(bf16_t)(b.y*s1.y*inv); o[2]=(bf16_t)(b.z*s1.z*inv); o[3]=(bf16_t)(b.w*s1.w*inv);
    xo[t + 256] = o;
    o[0]=(bf16_t)(c.x*s2.x*inv); o[1]=(bf16_t)(c.y*s2.y*inv); o[2]=(bf16_t)(c.z*s2.z*inv); o[3]=(bf16_t)(c.w*s2.w*inv);
    xo[t + 512] = o;
}

// ============  weight transpose fp32 (K x N) -> bf16 B^T (N x K)  ============
__global__ void transpose_conv(const float* __restrict__ in, bf16_t* __restrict__ out, int K, int N)
{
    __shared__ float tile[32][33];
    const int n0 = blockIdx.x * 32, k0 = blockIdx.y * 32;
    const int tx = threadIdx.x, ty = threadIdx.y;
    #pragma unroll
    for (int i = 0; i < 32; i += 8)
        tile[ty + i][tx] = in[(size_t)(k0 + ty + i) * N + n0 + tx];
    __syncthreads();
    #pragma unroll
    for (int i = 0; i < 32; i += 8)
        out[(size_t)(n0 + ty + i) * K + k0 + tx] = (bf16_t)tile[tx][ty + i];
}

// ==================  plain fp32 -> bf16 conversion (w_o)  ==================
__global__ void conv_bf16(const float* __restrict__ in, bf16_t* __restrict__ out, int n4)
{
    const int stride = gridDim.x * 256;
    for (int i = blockIdx.x * 256 + threadIdx.x; i < n4; i += stride) {
        float4 v = ((const float4*)in)[i];
        bf16x4 o;
        o[0] = (bf16_t)v.x; o[1] = (bf16_t)v.y; o[2] = (bf16_t)v.z; o[3] = (bf16_t)v.w;
        ((bf16x4*)out)[i] = o;
    }
}

// ==========================  256x256 8-phase GEMM  ==========================
template<int CFP>
__device__ __forceinline__ void mfma16(f32x4 (&acc)[8][4], const bf16x8 (&af)[8],
                                       const bf16x8 (&bfv)[2]) {
    __builtin_amdgcn_s_setprio(1);
    #pragma unroll
    for (int rf = 0; rf < 8; ++rf) {
        acc[rf][2*CFP]   = __builtin_amdgcn_mfma_f32_16x16x32_bf16(af[rf], bfv[0], acc[rf][2*CFP],   0, 0, 0);
        acc[rf][2*CFP+1] = __builtin_amdgcn_mfma_f32_16x16x32_bf16(af[rf], bfv[1], acc[rf][2*CFP+1], 0, 0, 0);
    }
    __builtin_amdgcn_s_setprio(0);
}

__global__ __launch_bounds__(512, 2) void gemm256(
    const bf16_t* __restrict__ A, const bf16_t* __restrict__ B, int N, int K,
    float* __restrict__ Cf, int ldf, int flo, int fhi,
    bf16_t* __restrict__ Cb1, int ldb1, int b1lo, int b1hi,
    bf16_t* __restrict__ Cb2, int ldb2, int b2lo, int b2hi)
{
    __shared__ char LDS[131072];
    char* Lc = LDS;
    const int tid = threadIdx.x;
    const int wv = tid >> 6, lane = tid & 63;
    const int fr = lane & 15, fg = lane >> 4;
    const int wr = wv >> 2, wc = wv & 3;                  // 2 x 4 wave grid
    const int m0 = blockIdx.y << 8, n0 = blockIdx.x << 8;
    const uint32_t slot4 = (uint32_t)((fg ^ ((fr >> 1) & 3)) << 4);  // swizzled 16B slot

    int grow[2], gcol[2];
    const bf16_t* agp[2]; const bf16_t* bgp[2];
    uint32_t aoff[2], boff[2];
    #pragma unroll
    for (int j = 0; j < 2; ++j) {
        const int c = j * 512 + tid;
        const int g = c ^ ((c >> 3) & 3);                 // pre-swizzled source chunk
        grow[j] = g >> 2; gcol[j] = g & 3;
        agp[j] = A + (size_t)(m0 + grow[j]) * K + gcol[j] * 8;
        int br = n0 + grow[j]; if (br > N - 1) br = N - 1;
        bgp[j] = B + (size_t)br * K + gcol[j] * 8;
        aoff[j] = (uint32_t)((j * 8 + wv) * 1024);
        boff[j] = (uint32_t)(65536 + (j * 8 + wv) * 1024);
    }

    f32x4 acc[8][4];
    f32x4 zero = {0.f, 0.f, 0.f, 0.f};
    #pragma unroll
    for (int i = 0; i < 8; ++i)
        #pragma unroll
        for (int j = 0; j < 4; ++j) acc[i][j] = zero;

    bf16x8 af[8], bfv[2];
    const int rowA = (wr << 7) + fr;
    const int rowB = (wc << 6) + fr;

    auto stA = [&](int t, int kh) {
        const uint32_t sb = (uint32_t)(((2*t + kh) & 3) << 14);
        #pragma unroll
        for (int j = 0; j < 2; ++j)
            async_ld16(agp[j] + t * 64 + kh * 32, Lc + sb + aoff[j]);
    };
    auto stB = [&](int t, int kh) {
        const uint32_t sb = (uint32_t)(((2*t + kh) & 3) << 14);
        #pragma unroll
        for (int j = 0; j < 2; ++j)
            async_ld16(bgp[j] + t * 64 + kh * 32, Lc + sb + boff[j]);
    };
    auto ldA8 = [&](int t, int kh) {
        const uint32_t base = (uint32_t)(((2*t + kh) & 3) << 14);
        #pragma unroll
        for (int rf = 0; rf < 8; ++rf)
            af[rf] = *(const bf16x8*)(Lc + base + (rowA + rf * 16) * 64 + slot4);
    };
    auto ldB2 = [&](int t, int kh, int cfp) {
        const uint32_t base = (uint32_t)(65536 + (((2*t + kh) & 3) << 14));
        #pragma unroll
        for (int c = 0; c < 2; ++c)
            bfv[c] = *(const bf16x8*)(Lc + base + (rowB + (cfp * 2 + c) * 16) * 64 + slot4);
    };

    const int NT = K >> 6, nIter = NT >> 1;
    stA(0, 0); stB(0, 0); stA(0, 1); stB(0, 1); stA(1, 0); stB(1, 0);
    WAITV4(); BARRIER();

    for (int i = 0; i < nIter; ++i) {
        const int t0 = 2 * i, t1 = t0 + 1, t2 = t0 + 2, t3 = t0 + 3;
        const bool pref = (i < nIter - 1);
        ldA8(t0, 0); ldB2(t0, 0, 0); stA(t1, 1);
        BARRIER(); mfma16<0>(acc, af, bfv); BARRIER();
        ldB2(t0, 0, 1); stB(t1, 1);
        BARRIER(); mfma16<1>(acc, af, bfv); BARRIER();
        ldA8(t0, 1); ldB2(t0, 1, 0); if (pref) stA(t2, 0);
        BARRIER(); mfma16<0>(acc, af, bfv); BARRIER();
        ldB2(t0, 1, 1); if (pref) stB(t2, 0);
        if (pref) { WAITV4(); } else { WAITV0(); }
        BARRIER(); mfma16<1>(acc, af, bfv); BARRIER();
        ldA8(t1, 0); ldB2(t1, 0, 0); if (pref) stA(t2, 1);
        BARRIER(); mfma16<0>(acc, af, bfv); BARRIER();
        ldB2(t1, 0, 1); if (pref) stB(t2, 1);
        BARRIER(); mfma16<1>(acc, af, bfv); BARRIER();
        ldA8(t1, 1); ldB2(t1, 1, 0); if (pref) stA(t3, 0);
        BARRIER(); mfma16<0>(acc, af, bfv); BARRIER();
        ldB2(t1, 1, 1); if (pref) stB(t3, 0);
        WAITV4();
        BARRIER(); mfma16<1>(acc, af, bfv); BARRIER();
    }

    const int colb = n0 + (wc << 6) + fr;
    const int rowb = m0 + (wr << 7) + fg * 4;
    #pragma unroll
    for (int rf = 0; rf < 8; ++rf)
        #pragma unroll
        for (int cf = 0; cf < 4; ++cf) {
            const int col = colb + cf * 16;
            #pragma unroll
            for (int r = 0; r < 4; ++r) {
                const int row = rowb + rf * 16 + r;
                const float v = acc[rf][cf][r];
                if (Cf  && col >= flo  && col < fhi)  Cf [(size_t)row * ldf  + col - flo]  = v;
                if (Cb1 && col >= b1lo && col < b1hi) Cb1[(size_t)row * ldb1 + col - b1lo] = (bf16_t)v;
                if (Cb2 && col >= b2lo && col < b2hi) Cb2[(size_t)row * ldb2 + col - b2lo] = (bf16_t)v;
            }
        }
}

// =========================  RoPE tables (fp32)  =========================
__global__ void rope_tab(float* __restrict__ ctab, float* __restrict__ stab)
{
    const int idx = blockIdx.x * 256 + threadIdx.x;
    if (idx >= S_LEN * 32) return;
    const int s = idx >> 5, i = idx & 31;
    const float freq = powf(10000.0f, -(float)(2 * i) * (1.0f / 128.0f));
    const float ang = (float)s * freq;
    ctab[idx] = cosf(ang);
    stab[idx] = sinf(ang);
}

// =================  RoPE on Q (in-place, dims 64..127/head)  =================
__global__ void rope_q_kernel(bf16_t* __restrict__ q, const float* __restrict__ ctab,
                              const float* __restrict__ stab)
{
    const int idx = blockIdx.x * 256 + threadIdx.x;
    if (idx >= NTOK * N_HEADS * 32) return;
    const int i = idx & 31;
    const int rest = idx >> 5;
    const int h = rest % N_HEADS;
    const int tok = rest / N_HEADS;
    const int s = tok & (S_LEN - 1);
    bf16_t* p = q + (size_t)tok * D_MODEL + h * HEAD_DIM + 64;
    const float a = (float)p[i], b = (float)p[i + 32];
    const float c = ctab[s * 32 + i], sn = stab[s * 32 + i];
    p[i]      = (bf16_t)(a * c - b * sn);
    p[i + 32] = (bf16_t)(b * c + a * sn);
}

// ==========  RoPE on shared K-rope (reads kv_down fp32 output)  ==========
__global__ void rope_k_kernel(const float* __restrict__ kvd, bf16_t* __restrict__ kr,
                              const float* __restrict__ ctab, const float* __restrict__ stab)
{
    const int idx = blockIdx.x * 256 + threadIdx.x;
    if (idx >= NTOK * 32) return;
    const int i = idx & 31;
    const int tok = idx >> 5;
    const int s = tok & (S_LEN - 1);
    const float* p = kvd + (size_t)tok * KVDN + KV_PROJ;
    const float a = p[i], b = p[i + 32];
    const float c = ctab[s * 32 + i], sn = stab[s * 32 + i];
    kr[(size_t)tok * 64 + i]      = (bf16_t)(a * c - b * sn);
    kr[(size_t)tok * 64 + i + 32] = (bf16_t)(b * c + a * sn);
}

// ======  V transpose: VT[bh][d][s] = kv_up[b, s, h*192 + 64 + d]  ======
__global__ void vt_asm(const bf16_t* __restrict__ kvup, bf16_t* __restrict__ vt)
{
    __shared__ bf16_t tile[32][33];
    const int s0 = blockIdx.x * 32, d0 = blockIdx.y * 32, bh = blockIdx.z;
    const int b = bh / N_HEADS, h = bh % N_HEADS;
    const int tx = threadIdx.x, ty = threadIdx.y;
    #pragma unroll
    for (int i = 0; i < 32; i += 8)
        tile[ty + i][tx] = kvup[(size_t)(b * S_LEN + s0 + ty + i) * KVUN + h * 192 + 64 + d0 + tx];
    __syncthreads();
    #pragma unroll
    for (int i = 0; i < 32; i += 8)
        vt[((size_t)bh * HEAD_DIM + d0 + ty + i) * S_LEN + s0 + tx] = tile[tx][ty + i];
}

// ===============  causal flash attention v3 (swapped QK, reg-P)  ===============
// Block = 128 q-rows (4 waves x 32), tile pair {x, 15-x}. K/Krp/V double-buffered.
// QK^T swapped: D[kv, q] = mfma(Kfrag, Qfrag) -> lane owns 1 q-row per rf,
// softmax in-lane + 2 shfl. PV: D2[d, q] = mfma(VTfrag, Pfrag), P in regs.
__global__ __launch_bounds__(256, 2) void attn_fwd(
    const bf16_t* __restrict__ Q, const bf16_t* __restrict__ KVUP,
    const bf16_t* __restrict__ KR, const bf16_t* __restrict__ VT,
    bf16_t* __restrict__ AO)
{
    __shared__ bf16_t Knr[2][64 * 64];
    __shared__ bf16_t Krp[2][64 * 64];
    __shared__ bf16_t Vls[2][128 * 64];

    const int bh = blockIdx.y;
    const int b = bh / N_HEADS, h = bh % N_HEADS;
    const int wave = threadIdx.x >> 6, lane = threadIdx.x & 63;
    const int fr = lane & 15, fg = lane >> 4;
    const int rx = fr & 7;
    const int hi = fg >> 1;                       // P-frag source-plane select
    const int s0l = fr + 32 * (fg & 1);           // P-frag source lanes
    const int s1l = s0l + 16;

    const bf16_t* Kb  = KVUP + (size_t)b * S_LEN * KVUN + (size_t)h * 192;
    const bf16_t* KRb = KR + (size_t)b * S_LEN * 64;
    const bf16_t* Vb  = VT + (size_t)bh * HEAD_DIM * S_LEN;

    const int srow   = lane >> 3;
    const int schunk = (lane & 7) ^ srow;
    const float l2e_isc = 0.127500625f;           // (1/sqrt(128)) * log2(e)

    f32x4 zero = {0.f, 0.f, 0.f, 0.f};

    #pragma unroll 1
    for (int tp = 0; tp < 2; ++tp) {
        const int qt = (tp == 0) ? blockIdx.x : (15 - blockIdx.x);
        const int qb = qt * 128;
        const int wrow0 = qb + wave * 32;

        bf16x8 qf[2][4];
        #pragma unroll
        for (int rf = 0; rf < 2; ++rf)
            #pragma unroll
            for (int kc = 0; kc < 4; ++kc)
                qf[rf][kc] = *(const bf16x8*)(Q + (size_t)(b * S_LEN + wrow0 + rf * 16 + fr) * D_MODEL
                                              + h * HEAD_DIM + kc * 32 + fg * 8);
        f32x4 oacc[2][8];
        float m_i[2], l_i[2];
        #pragma unroll
        for (int rf = 0; rf < 2; ++rf) {
            #pragma unroll
            for (int nf = 0; nf < 8; ++nf) oacc[rf][nf] = zero;
            m_i[rf] = -1e30f; l_i[rf] = 0.f;
        }

        // ---- staging helper: stage 64-kv step into buffer bf ----
        auto stage = [&](int kvb, int bf) {
            #pragma unroll
            for (int c = 0; c < 2; ++c) {
                const int r0 = wave * 16 + c * 8;
                async_ld16(Kb  + (size_t)(kvb + r0 + srow) * KVUN + schunk * 8, &Knr[bf][r0 * 64]);
                async_ld16(KRb + (size_t)(kvb + r0 + srow) * 64   + schunk * 8, &Krp[bf][r0 * 64]);
            }
            #pragma unroll
            for (int c = 0; c < 4; ++c) {
                const int r0 = wave * 32 + c * 8;
                async_ld16(Vb + (size_t)(r0 + srow) * S_LEN + kvb + schunk * 8, &Vls[bf][r0 * 64]);
            }
        };

        const int kvend = qb + 128;
        int cur = 0;
        stage(0, 0);
        __syncthreads();                 // drains vmcnt, publishes buf0

        #pragma unroll 1
        for (int kvb = 0; kvb < kvend; kvb += 64) {
            if (kvb + 64 < kvend) stage(kvb + 64, cur ^ 1);   // issue-early prefetch

            if (kvb <= wrow0 + 31) {
                const bf16_t* Kc = Knr[cur];
                const bf16_t* Rc = Krp[cur];
                const bf16_t* Vc = Vls[cur];

                // ---- QK^T swapped: sacc[rf][jn] = D[kv-tile jn, q-tile rf] ----
                f32x4 sacc[2][4];
                #pragma unroll
                for (int rf = 0; rf < 2; ++rf)
                    #pragma unroll
                    for (int jn = 0; jn < 4; ++jn) sacc[rf][jn] = zero;
                #pragma unroll
                for (int jn = 0; jn < 4; ++jn) {
                    const int krow = jn * 16 + fr;
                    bf16x8 kA = *(const bf16x8*)(Kc + krow * 64 + (((0 + fg) ^ rx) << 3));
                    bf16x8 kB = *(const bf16x8*)(Kc + krow * 64 + (((4 + fg) ^ rx) << 3));
                    bf16x8 kC = *(const bf16x8*)(Rc + krow * 64 + (((0 + fg) ^ rx) << 3));
                    bf16x8 kD = *(const bf16x8*)(Rc + krow * 64 + (((4 + fg) ^ rx) << 3));
                    #pragma unroll
                    for (int rf = 0; rf < 2; ++rf) {
                        sacc[rf][jn] = __builtin_amdgcn_mfma_f32_16x16x32_bf16(kA, qf[rf][0], sacc[rf][jn], 0, 0, 0);
                        sacc[rf][jn] = __builtin_amdgcn_mfma_f32_16x16x32_bf16(kB, qf[rf][1], sacc[rf][jn], 0, 0, 0);
                        sacc[rf][jn] = __builtin_amdgcn_mfma_f32_16x16x32_bf16(kC, qf[rf][2], sacc[rf][jn], 0, 0, 0);
                        sacc[rf][jn] = __builtin_amdgcn_mfma_f32_16x16x32_bf16(kD, qf[rf][3], sacc[rf][jn], 0, 0, 0);
                    }
                }

                // ---- softmax: lane owns q-row (wrow0+rf*16+fr); kv = kvb+jn*16+fg*4+r ----
                const bool needMask = (kvb + 63 > wrow0);
                uint32_t pk[2][4][2];
                float scf[2];
                #pragma unroll
                for (int rf = 0; rf < 2; ++rf) {
                    const int qrow = wrow0 + rf * 16 + fr;
                    float mx = -1e30f;
                    #pragma unroll
                    for (int jn = 0; jn < 4; ++jn)
                        #pragma unroll
                        for (int r = 0; r < 4; ++r) {
                            float v = sacc[rf][jn][r] * l2e_isc;
                            if (needMask && (kvb + jn * 16 + fg * 4 + r > qrow)) v = -1e30f;
                            sacc[rf][jn][r] = v;
                            mx = fmaxf(mx, v);
                        }
                    mx = fmaxf(mx, __shfl_xor(mx, 16));
                    mx = fmaxf(mx, __shfl_xor(mx, 32));
                    const float mn = fmaxf(m_i[rf], mx);
                    scf[rf] = __builtin_amdgcn_exp2f(m_i[rf] - mn);
                    m_i[rf] = mn;
                    float ls = 0.f;
                    #pragma unroll
                    for (int jn = 0; jn < 4; ++jn) {
                        float p0 = __builtin_amdgcn_exp2f(sacc[rf][jn][0] - mn);
                        float p1 = __builtin_amdgcn_exp2f(sacc[rf][jn][1] - mn);
                        float p2 = __builtin_amdgcn_exp2f(sacc[rf][jn][2] - mn);
                        float p3 = __builtin_amdgcn_exp2f(sacc[rf][jn][3] - mn);
                        ls += (p0 + p1) + (p2 + p3);
                        union { bf16x4 h; uint32_t w[2]; } cv;
                        cv.h[0] = (bf16_t)p0; cv.h[1] = (bf16_t)p1;
                        cv.h[2] = (bf16_t)p2; cv.h[3] = (bf16_t)p3;
                        pk[rf][jn][0] = cv.w[0]; pk[rf][jn][1] = cv.w[1];
                    }
                    ls += __shfl_xor(ls, 16);
                    ls += __shfl_xor(ls, 32);
                    l_i[rf] = l_i[rf] * scf[rf] + ls;
                    #pragma unroll
                    for (int nf = 0; nf < 8; ++nf)
                        #pragma unroll
                        for (int r = 0; r < 4; ++r) oacc[rf][nf][r] *= scf[rf];
                }

                // ---- build PV B-fragments from registers (cross-lane shfl) ----
                bf16x8 bfr[2][2];
                #pragma unroll
                for (int rf = 0; rf < 2; ++rf)
                    #pragma unroll
                    for (int ks = 0; ks < 2; ++ks) {
                        const uint32_t t00 = __shfl(pk[rf][2*ks][0],   s0l);
                        const uint32_t t01 = __shfl(pk[rf][2*ks][1],   s0l);
                        const uint32_t t10 = __shfl(pk[rf][2*ks+1][0], s0l);
                        const uint32_t t11 = __shfl(pk[rf][2*ks+1][1], s0l);
                        const uint32_t u00 = __shfl(pk[rf][2*ks][0],   s1l);
                        const uint32_t u01 = __shfl(pk[rf][2*ks][1],   s1l);
                        const uint32_t u10 = __shfl(pk[rf][2*ks+1][0], s1l);
                        const uint32_t u11 = __shfl(pk[rf][2*ks+1][1], s1l);
                        union { bf16x8 h; uint32_t w[4]; } bb;
                        bb.w[0] = hi ? t10 : t00;
                        bb.w[1] = hi ? t11 : t01;
                        bb.w[2] = hi ? u10 : u00;
                        bb.w[3] = hi ? u11 : u01;
                        bfr[rf][ks] = bb.h;
                    }

                // ---- PV: oacc[rf][nf] = D2[d-tile nf, q-tile rf] ----
                #pragma unroll
                for (int nf = 0; nf < 8; ++nf) {
                    const int vrow = nf * 16 + fr;
                    bf16x8 v0 = *(const bf16x8*)(Vc + vrow * 64 + (((0 + fg) ^ rx) << 3));
                    bf16x8 v1 = *(const bf16x8*)(Vc + vrow * 64 + (((4 + fg) ^ rx) << 3));
                    #pragma unroll
                    for (int rf = 0; rf < 2; ++rf) {
                        oacc[rf][nf] = __builtin_amdgcn_mfma_f32_16x16x32_bf16(v0, bfr[rf][0], oacc[rf][nf], 0, 0, 0);
                        oacc[rf][nf] = __builtin_amdgcn_mfma_f32_16x16x32_bf16(v1, bfr[rf][1], oacc[rf][nf], 0, 0, 0);
                    }
                }
            }
            __syncthreads();             // publish prefetch, retire reads of cur
            cur ^= 1;
        }

        // ---- epilogue: normalize + vectorized store (d-contiguous per reg) ----
        #pragma unroll
        for (int rf = 0; rf < 2; ++rf) {
            const float rl = __builtin_amdgcn_rcpf(l_i[rf]);
            const int qrow = wrow0 + rf * 16 + fr;
            bf16_t* aob = AO + (size_t)(b * S_LEN + qrow) * D_MODEL + h * HEAD_DIM + fg * 4;
            #pragma unroll
            for (int nf = 0; nf < 8; ++nf) {
                bf16x4 o;
                o[0] = (bf16_t)(oacc[rf][nf][0] * rl);
                o[1] = (bf16_t)(oacc[rf][nf][1] * rl);
                o[2] = (bf16_t)(oacc[rf][nf][2] * rl);
                o[3] = (bf16_t)(oacc[rf][nf][3] * rl);
                *(bf16x4*)(aob + nf * 16) = o;
            }
        }
    }
}

// ============================  launch  ============================
extern "C" void kernel_launch(void* const* d_in, const int* in_sizes, int n_in,
                              void* d_out, int out_size, void* d_ws, size_t ws_size,
                              hipStream_t stream)
{
    const float* x     = (const float*)d_in[0];
    const float* scale = (const float*)d_in[1];
    const float* w_dq  = (const float*)d_in[2];
    const float* w_uq  = (const float*)d_in[3];
    const float* w_dkv = (const float*)d_in[4];
    const float* w_ukv = (const float*)d_in[5];
    const float* w_o   = (const float*)d_in[6];
    float* out0 = (float*)d_out;                        // (4096, 3072)
    float* out1 = out0 + (size_t)NTOK * D_MODEL;        // (4096, 2112)

    if (ws_size < 187039744ull) return;
    char* ws = (char*)d_ws;
    bf16_t* XN    = (bf16_t*)(ws + 0);
    bf16_t* WCAT  = (bf16_t*)(ws + 25165824ull);        // [3648][3072] b^T (dq|dkv)
    bf16_t* WUQT  = (bf16_t*)(ws + 47579136ull);
    bf16_t* WUKVT = (bf16_t*)(ws + 57016320ull);
    bf16_t* WOB   = (bf16_t*)(ws + 75890688ull);
    bf16_t* QD    = (bf16_t*)(ws + 94765056ull);
    bf16_t* Qb    = (bf16_t*)(ws + 107347968ull);
    bf16_t* KVNR  = (bf16_t*)(ws + 132513792ull);
    bf16_t* KVUP  = (bf16_t*)(ws + 149291008ull);
    bf16_t* KRB   = (bf16_t*)(ws + 94765056ull);        // aliases QD (after q_up)
    float*  CTAB  = (float*) (ws + 95289344ull);
    float*  STAB  = (float*) (ws + 95551488ull);
    bf16_t* VTb   = WCAT;                               // reuses WCAT (after kv_up)
    bf16_t* AO    = XN;

    rmsnorm_kernel<<<NTOK, 256, 0, stream>>>(x, scale, XN);
    transpose_conv<<<dim3(1536/32, 3072/32), dim3(32,8), 0, stream>>>(w_dq,  WCAT, 3072, 1536);
    transpose_conv<<<dim3(2112/32, 3072/32), dim3(32,8), 0, stream>>>(w_dkv, WCAT + (size_t)1536*3072, 3072, 2112);
    transpose_conv<<<dim3(3072/32, 1536/32), dim3(32,8), 0, stream>>>(w_uq,  WUQT, 1536, 3072);
    transpose_conv<<<dim3(4608/32, 2048/32), dim3(32,8), 0, stream>>>(w_ukv, WUKVT, 2048, 4608);
    conv_bf16<<<2048, 256, 0, stream>>>(w_o, WOB, (D_MODEL * D_MODEL) / 4);

    gemm256<<<dim3(15, 16), 512, 0, stream>>>(XN, WCAT, 3648, 3072,
        out1, KVDN, 1536, 3648,
        QD,   Q_PROJ, 0, 1536,
        KVNR, KV_PROJ, 1536, 3584);
    gemm256<<<dim3(12, 16), 512, 0, stream>>>(QD, WUQT, 3072, 1536,
        nullptr, 0, 0, 0, Qb, D_MODEL, 0, 3072, nullptr, 0, 0, 0);
    rope_tab<<<(S_LEN * 32 + 255) / 256, 256, 0, stream>>>(CTAB, STAB);
    rope_q_kernel<<<(NTOK * N_HEADS * 32 + 255) / 256, 256, 0, stream>>>(Qb, CTAB, STAB);
    rope_k_kernel<<<(NTOK * 32 + 255) / 256, 256, 0, stream>>>(out1, KRB, CTAB, STAB);
    gemm256<<<dim3(18, 16), 512, 0, stream>>>(KVNR, WUKVT, 4608, 2048,
        nullptr, 0, 0, 0, KVUP, KVUN, 0, 4608, nullptr, 0, 0, 0);
    vt_asm<<<dim3(S_LEN/32, HEAD_DIM/32, 48), dim3(32,8), 0, stream>>>(KVUP, VTb);
    attn_fwd<<<dim3(8, 48), 256, 0, stream>>>(Qb, KVUP, KRB, VTb, AO);
    gemm256<<<dim3(12, 16), 512, 0, stream>>>(AO, WOB, 3072, 3072,
        out0, D_MODEL, 0, 3072, nullptr, 0, 0, 0, nullptr, 0, 0, 0);
}